// Round 19
// baseline (306.988 us; speedup 1.0000x reference)
//
#include <hip/hip_runtime.h>

#define NELEM 10
#define C 128
#define RWS 544   // packed row stride in ushorts: 512 bf16 R + 32 ushorts (16 f32) Y

typedef __bf16 bf16x8 __attribute__((ext_vector_type(8)));
typedef float f32x4 __attribute__((ext_vector_type(4)));

__device__ inline unsigned short f2bf(float f) {
    unsigned x = __float_as_uint(f);
    unsigned r = (x + 0x7fffu + ((x >> 16) & 1u)) >> 16;
    return (unsigned short)r;
}
__device__ inline float bf2f(unsigned short b) {
    return __uint_as_float(((unsigned)b) << 16);
}

// ---------------- small prep kernels ----------------

__global__ __launch_bounds__(128) void k_tables(
    const float* __restrict__ W_embed, const float* __restrict__ W_up,
    const float* __restrict__ W_skip,
    float* __restrict__ h_elem, float* __restrict__ sc0e) {
    const int a = blockIdx.x;
    const int c = threadIdx.x;
    float acc = 0.f, acc2 = 0.f;
#pragma unroll 4
    for (int k = 0; k < C; ++k) {
        float we = W_embed[a * C + k];
        acc  = fmaf(we, W_up[k * C + c], acc);
        acc2 = fmaf(we, W_skip[(k * NELEM + a) * C + c], acc2);
    }
    h_elem[a * C + c] = acc;
    sc0e[a * C + c] = acc2;
}

__global__ void k_elem(const float* __restrict__ x, int* __restrict__ elem, int n) {
    int i = blockIdx.x * 256 + threadIdx.x;
    if (i >= n) return;
    int a = 0;
    float best = x[i * NELEM];
    for (int j = 1; j < NELEM; ++j) {
        float v = x[i * NELEM + j];
        if (v > best) { best = v; a = j; }
    }
    elem[i] = a;
}

// pack Wr4 -> MFMA A-fragments (W^T tiles), bf16 (32 ctiles):
__global__ void k_wprep(const float* __restrict__ Wr4, unsigned short* __restrict__ WbT) {
    int idx = blockIdx.x * 256 + threadIdx.x;   // 32768
    int j = idx & 7;
    int l = (idx >> 3) & 63;
    int ks = (idx >> 9) & 1;
    int ctile = idx >> 10;
    int k = ks * 32 + (l >> 4) * 8 + j;
    int c = ctile * 16 + (l & 15);
    WbT[idx] = f2bf(Wr4[k * 512 + c]);
}

// pack Wr2,Wr3 (64x64) -> MFMA A-fragments, bf16 (4 ctiles each)
__global__ void k_wprep23(const float* __restrict__ Wr2, const float* __restrict__ Wr3,
                          unsigned short* __restrict__ WbA) {
    int idx = blockIdx.x * 256 + threadIdx.x;   // 8192
    int which = idx >> 12;
    int r = idx & 4095;
    int j = r & 7;
    int l = (r >> 3) & 63;
    int ks = (r >> 9) & 1;
    int ct = (r >> 10) & 3;
    const float* W = which ? Wr3 : Wr2;
    int k = ks * 32 + (l >> 4) * 8 + j;
    int c = ct * 16 + (l & 15);
    WbA[idx] = f2bf(W[k * 64 + c]);
}

// ---------------- CSR build (offsets + inverse permutation + sender element) ----------------

__global__ void k_hist(const int* __restrict__ ei, const int* __restrict__ elem,
                       int* __restrict__ deg, int* __restrict__ eel, int E) {
    int e = blockIdx.x * 256 + threadIdx.x;
    if (e < E) {
        atomicAdd(&deg[ei[E + e]], 1);
        eel[e] = elem[ei[e]];
    }
}

__global__ void k_scan(const int* __restrict__ deg, int* __restrict__ offs, int n) {
    __shared__ int sums[1024];
    int tid = threadIdx.x;
    int base = tid * 8;
    int loc[8];
    int s = 0;
#pragma unroll
    for (int i = 0; i < 8; ++i) {
        loc[i] = s;
        if (base + i < n) s += deg[base + i];
    }
    sums[tid] = s;
    __syncthreads();
    for (int st = 1; st < 1024; st <<= 1) {
        int v = 0;
        if (tid >= st) v = sums[tid - st];
        __syncthreads();
        sums[tid] += v;
        __syncthreads();
    }
    int excl = sums[tid] - s;
#pragma unroll
    for (int i = 0; i < 8; ++i)
        if (base + i < n) offs[base + i] = excl + loc[i];
    if (tid == 1023) offs[n] = sums[1023];
}

__global__ void k_scatter(const int* __restrict__ ei, const int* __restrict__ offs,
                          int* __restrict__ cur, int* __restrict__ epos, int E) {
    int e = blockIdx.x * 256 + threadIdx.x;
    if (e < E) {
        int r = ei[E + e];
        int p = atomicAdd(&cur[r], 1);
        epos[e] = offs[r] + p;
    }
}

// ---------------- edge pre-kernel: Y + radial + layer 1 only ----------------

__global__ __launch_bounds__(256, 2) void k_edge_pre(
    const float* __restrict__ evec, const float* __restrict__ elen,
    const float* __restrict__ Wr1,
    float* __restrict__ Yw, unsigned short* __restrict__ T1b, int E)
{
    const int tid = threadIdx.x;
    const int e = blockIdx.x * 256 + tid;
    if (e >= E) return;

    float vx = evec[3 * e], vy = evec[3 * e + 1], vz = evec[3 * e + 2];
    float inv = rsqrtf(vx * vx + vy * vy + vz * vz);
    float ux = vx * inv, uy = vy * inv, uz = vz * inv;

    const float s3    = 1.7320508075688772f;
    const float s5h   = 1.118033988749895f;
    const float s15   = 3.872983346207417f;
    const float s15h  = 1.9364916731037085f;
    const float s70_4 = 2.091650066335189f;
    const float s105  = 10.246950765959598f;
    const float s105_2= 5.123475382979799f;
    const float s42_4 = 1.6201851746019651f;
    const float s7_2  = 1.3228756555322954f;

    float xx = ux * ux, yy = uy * uy, zz = uz * uz;
    float4* yo = reinterpret_cast<float4*>(Yw + ((size_t)e << 4));
    yo[0] = make_float4(1.0f, s3 * ux, s3 * uy, s3 * uz);
    yo[1] = make_float4(s15 * ux * uy, s15 * uy * uz, s5h * (3.0f * zz - 1.0f), s15 * ux * uz);
    yo[2] = make_float4(s15h * (xx - yy),
                        s70_4 * uy * (3.0f * xx - yy),
                        s105 * ux * uy * uz,
                        s42_4 * uy * (5.0f * zz - 1.0f));
    yo[3] = make_float4(s7_2 * uz * (5.0f * zz - 3.0f),
                        s42_4 * ux * (5.0f * zz - 1.0f),
                        s105_2 * uz * (xx - yy),
                        s70_4 * ux * (xx - 3.0f * yy));

    float r = elen[e];
    float u = r * 0.2f;
    float u2 = u * u;
    float u5 = u2 * u2 * u;
    float env = 1.0f - 21.0f * u5 + 35.0f * u5 * u - 15.0f * u5 * u2;
    if (u >= 1.0f) env = 0.0f;
    float th = 3.14159265358979323846f * u;
    float s1 = __sinf(th), c1 = __cosf(th);
    float pref = 0.6324555320336759f * env / r;
    float ef[8];
    float sn = s1, cn = c1;
    ef[0] = pref * sn;
#pragma unroll
    for (int nn = 1; nn < 8; ++nn) {
        float sn1 = sn * c1 + cn * s1;
        float cn1 = cn * c1 - sn * s1;
        sn = sn1; cn = cn1;
        ef[nn] = pref * sn;
    }

    // layer 1: 8 -> 64 + silu
    float t[64];
#pragma unroll
    for (int j = 0; j < 64; ++j) t[j] = 0.0f;
#pragma unroll
    for (int i = 0; i < 8; ++i) {
        const float4* w1r = reinterpret_cast<const float4*>(Wr1 + i * 64);
        float efi = ef[i];
#pragma unroll
        for (int j4 = 0; j4 < 16; ++j4) {
            float4 w = w1r[j4];
            t[4 * j4 + 0] = fmaf(efi, w.x, t[4 * j4 + 0]);
            t[4 * j4 + 1] = fmaf(efi, w.y, t[4 * j4 + 1]);
            t[4 * j4 + 2] = fmaf(efi, w.z, t[4 * j4 + 2]);
            t[4 * j4 + 3] = fmaf(efi, w.w, t[4 * j4 + 3]);
        }
    }
#pragma unroll
    for (int j = 0; j < 64; ++j) {
        float v = t[j];
        t[j] = v * __builtin_amdgcn_rcpf(1.0f + __expf(-v));
    }

    // store T1 as MFMA B-fragments
    {
        const int etile = e >> 4, cc = e & 15;
#pragma unroll
        for (int ks = 0; ks < 2; ++ks) {
#pragma unroll
            for (int q = 0; q < 4; ++q) {
                const float* tp = &t[ks * 32 + q * 8];
                unsigned d0 = (unsigned)f2bf(tp[0]) | ((unsigned)f2bf(tp[1]) << 16);
                unsigned d1 = (unsigned)f2bf(tp[2]) | ((unsigned)f2bf(tp[3]) << 16);
                unsigned d2 = (unsigned)f2bf(tp[4]) | ((unsigned)f2bf(tp[5]) << 16);
                unsigned d3 = (unsigned)f2bf(tp[6]) | ((unsigned)f2bf(tp[7]) << 16);
                *reinterpret_cast<uint4*>(
                    T1b + (((size_t)(etile * 2 + ks) * 64) + q * 16 + cc) * 8) =
                    make_uint4(d0, d1, d2, d3);
            }
        }
    }
}

// ---------------- layers 2+3 via MFMA ----------------

__global__ __launch_bounds__(256) void k_l23m(
    const unsigned short* __restrict__ T1b, const unsigned short* __restrict__ WbA,
    unsigned short* __restrict__ Tb, int E)
{
    __shared__ unsigned short lb[4][32][72];
    const int lane = threadIdx.x & 63;
    const int wv = threadIdx.x >> 6;
    const int ebase = blockIdx.x * 128 + wv * 32;
    const int et0 = ebase >> 4;
    const int g = lane >> 4;
    const int rr = lane & 15;

    bf16x8 bt[2][2];
#pragma unroll
    for (int et = 0; et < 2; ++et)
#pragma unroll
        for (int ks = 0; ks < 2; ++ks)
            bt[et][ks] = *reinterpret_cast<const bf16x8*>(
                T1b + (((size_t)(et0 + et) * 2 + ks) * 64 + lane) * 8);

    const unsigned short* WA2 = WbA;
    const unsigned short* WA3 = WbA + 4096;
#pragma unroll
    for (int ct = 0; ct < 4; ++ct) {
        bf16x8 a0 = *reinterpret_cast<const bf16x8*>(WA2 + (((size_t)ct * 2 + 0) * 64 + lane) * 8);
        bf16x8 a1 = *reinterpret_cast<const bf16x8*>(WA2 + (((size_t)ct * 2 + 1) * 64 + lane) * 8);
#pragma unroll
        for (int et = 0; et < 2; ++et) {
            f32x4 acc = {0.f, 0.f, 0.f, 0.f};
            acc = __builtin_amdgcn_mfma_f32_16x16x32_bf16(a0, bt[et][0], acc, 0, 0, 0);
            acc = __builtin_amdgcn_mfma_f32_16x16x32_bf16(a1, bt[et][1], acc, 0, 0, 0);
            float v0 = acc[0] * __builtin_amdgcn_rcpf(1.0f + __expf(-acc[0]));
            float v1 = acc[1] * __builtin_amdgcn_rcpf(1.0f + __expf(-acc[1]));
            float v2 = acc[2] * __builtin_amdgcn_rcpf(1.0f + __expf(-acc[2]));
            float v3 = acc[3] * __builtin_amdgcn_rcpf(1.0f + __expf(-acc[3]));
            unsigned p0 = (unsigned)f2bf(v0) | ((unsigned)f2bf(v1) << 16);
            unsigned p1 = (unsigned)f2bf(v2) | ((unsigned)f2bf(v3) << 16);
            *reinterpret_cast<uint2*>(&lb[wv][et * 16 + rr][ct * 16 + g * 4]) =
                make_uint2(p0, p1);
        }
    }
    asm volatile("s_waitcnt lgkmcnt(0)" ::: "memory");
    __builtin_amdgcn_sched_barrier(0);

    bf16x8 bt2[2][2];
#pragma unroll
    for (int et = 0; et < 2; ++et)
#pragma unroll
        for (int ks = 0; ks < 2; ++ks)
            bt2[et][ks] = *reinterpret_cast<const bf16x8*>(
                &lb[wv][et * 16 + rr][ks * 32 + g * 8]);

#pragma unroll
    for (int ct = 0; ct < 4; ++ct) {
        bf16x8 a0 = *reinterpret_cast<const bf16x8*>(WA3 + (((size_t)ct * 2 + 0) * 64 + lane) * 8);
        bf16x8 a1 = *reinterpret_cast<const bf16x8*>(WA3 + (((size_t)ct * 2 + 1) * 64 + lane) * 8);
        int c0 = ct * 16 + g * 4;
        int ks3 = c0 >> 5;
        int q3 = (c0 >> 3) & 3;
        int joff = c0 & 7;
#pragma unroll
        for (int et = 0; et < 2; ++et) {
            f32x4 acc = {0.f, 0.f, 0.f, 0.f};
            acc = __builtin_amdgcn_mfma_f32_16x16x32_bf16(a0, bt2[et][0], acc, 0, 0, 0);
            acc = __builtin_amdgcn_mfma_f32_16x16x32_bf16(a1, bt2[et][1], acc, 0, 0, 0);
            float v0 = acc[0] * __builtin_amdgcn_rcpf(1.0f + __expf(-acc[0]));
            float v1 = acc[1] * __builtin_amdgcn_rcpf(1.0f + __expf(-acc[1]));
            float v2 = acc[2] * __builtin_amdgcn_rcpf(1.0f + __expf(-acc[2]));
            float v3 = acc[3] * __builtin_amdgcn_rcpf(1.0f + __expf(-acc[3]));
            unsigned p0 = (unsigned)f2bf(v0) | ((unsigned)f2bf(v1) << 16);
            unsigned p1 = (unsigned)f2bf(v2) | ((unsigned)f2bf(v3) << 16);
            *reinterpret_cast<uint2*>(
                Tb + (((size_t)(et0 + et) * 2 + ks3) * 64 + q3 * 16 + rr) * 8 + joff) =
                make_uint2(p0, p1);
        }
    }
}

// ---------------- layer-4 via MFMA ----------------

__global__ __launch_bounds__(256) void k_l4m(
    const unsigned short* __restrict__ Tb, const unsigned short* __restrict__ WbT,
    const int* __restrict__ eel, const int* __restrict__ epos,
    const float* __restrict__ h_elem, const float* __restrict__ Yw,
    unsigned short* __restrict__ Rw, int E)
{
    const int lane = threadIdx.x & 63;
    const int wv = threadIdx.x >> 6;
    const int ebase = blockIdx.x * 128 + wv * 32;
    const int et0 = ebase >> 4;

    bf16x8 bt[2][2];
#pragma unroll
    for (int et = 0; et < 2; ++et)
#pragma unroll
        for (int ks = 0; ks < 2; ++ks)
            bt[et][ks] = *reinterpret_cast<const bf16x8*>(
                Tb + (((size_t)(et0 + et) * 2 + ks) * 64 + lane) * 8);

    int a_[2], pe_[2];
#pragma unroll
    for (int et = 0; et < 2; ++et) {
        int e = ebase + et * 16 + (lane & 15);
        a_[et] = eel[e];
        pe_[et] = epos[e];
    }
    const int crow = (lane >> 4) * 4;

#pragma unroll 2
    for (int ctile = 0; ctile < 32; ++ctile) {
        bf16x8 aw0 = *reinterpret_cast<const bf16x8*>(
            WbT + (((size_t)ctile * 2 + 0) * 64 + lane) * 8);
        bf16x8 aw1 = *reinterpret_cast<const bf16x8*>(
            WbT + (((size_t)ctile * 2 + 1) * 64 + lane) * 8);
        int cb = ctile * 16 + crow;
        int ch = cb & 127;
#pragma unroll
        for (int et = 0; et < 2; ++et) {
            f32x4 acc = {0.f, 0.f, 0.f, 0.f};
            acc = __builtin_amdgcn_mfma_f32_16x16x32_bf16(aw0, bt[et][0], acc, 0, 0, 0);
            acc = __builtin_amdgcn_mfma_f32_16x16x32_bf16(aw1, bt[et][1], acc, 0, 0, 0);
            float4 h = *reinterpret_cast<const float4*>(h_elem + a_[et] * 128 + ch);
            float v0 = acc[0] * h.x, v1 = acc[1] * h.y;
            float v2 = acc[2] * h.z, v3 = acc[3] * h.w;
            unsigned p0 = (unsigned)f2bf(v0) | ((unsigned)f2bf(v1) << 16);
            unsigned p1 = (unsigned)f2bf(v2) | ((unsigned)f2bf(v3) << 16);
            *reinterpret_cast<uint2*>(Rw + (size_t)pe_[et] * RWS + cb) = make_uint2(p0, p1);
        }
    }

#pragma unroll
    for (int it = 0; it < 2; ++it) {
        int task = it * 64 + lane;
        int eo = task >> 2, sub = task & 3;
        int e = ebase + eo;
        int pe = epos[e];
        float4 y = *reinterpret_cast<const float4*>(Yw + ((size_t)e << 4) + sub * 4);
        *reinterpret_cast<float4*>(Rw + (size_t)pe * RWS + 512 + sub * 8) = y;
    }
}

// ---------------- gather: wave per node, NO LDS, NO barriers; m-major output ----------------

__global__ __launch_bounds__(256, 6) void k_agg(
    const int* __restrict__ offs, const unsigned short* __restrict__ Rw,
    float* __restrict__ agg, int N)
{
    const int lane = threadIdx.x & 63;
    const int wv = threadIdx.x >> 6;
    const int n = blockIdx.x * 4 + wv;
    const int beg = offs[n], end = offs[n + 1];

    float a0[16], a1[16];
#pragma unroll
    for (int m = 0; m < 16; ++m) { a0[m] = 0.f; a1[m] = 0.f; }

#pragma unroll 4
    for (int k = beg; k < end; ++k) {
        const unsigned short* row = Rw + (size_t)k * RWS;
        const ushort2* rw = reinterpret_cast<const ushort2*>(row);
        ushort2 r0 = rw[lane];
        ushort2 r1 = rw[64 + lane];
        ushort2 r2 = rw[128 + lane];
        ushort2 r3 = rw[192 + lane];
        const float4* Y4 = reinterpret_cast<const float4*>(row + 512);
        float4 y0 = Y4[0], y1 = Y4[1], y2 = Y4[2], y3 = Y4[3];
        float r0a = bf2f(r0.x), r0b = bf2f(r0.y);
        float r1a = bf2f(r1.x), r1b = bf2f(r1.y);
        float r2a = bf2f(r2.x), r2b = bf2f(r2.y);
        float r3a = bf2f(r3.x), r3b = bf2f(r3.y);
        a0[0]  = fmaf(r0a, y0.x, a0[0]);  a1[0]  = fmaf(r0b, y0.x, a1[0]);
        a0[1]  = fmaf(r1a, y0.y, a0[1]);  a1[1]  = fmaf(r1b, y0.y, a1[1]);
        a0[2]  = fmaf(r1a, y0.z, a0[2]);  a1[2]  = fmaf(r1b, y0.z, a1[2]);
        a0[3]  = fmaf(r1a, y0.w, a0[3]);  a1[3]  = fmaf(r1b, y0.w, a1[3]);
        a0[4]  = fmaf(r2a, y1.x, a0[4]);  a1[4]  = fmaf(r2b, y1.x, a1[4]);
        a0[5]  = fmaf(r2a, y1.y, a0[5]);  a1[5]  = fmaf(r2b, y1.y, a1[5]);
        a0[6]  = fmaf(r2a, y1.z, a0[6]);  a1[6]  = fmaf(r2b, y1.z, a1[6]);
        a0[7]  = fmaf(r2a, y1.w, a0[7]);  a1[7]  = fmaf(r2b, y1.w, a1[7]);
        a0[8]  = fmaf(r2a, y2.x, a0[8]);  a1[8]  = fmaf(r2b, y2.x, a1[8]);
        a0[9]  = fmaf(r3a, y2.y, a0[9]);  a1[9]  = fmaf(r3b, y2.y, a1[9]);
        a0[10] = fmaf(r3a, y2.z, a0[10]); a1[10] = fmaf(r3b, y2.z, a1[10]);
        a0[11] = fmaf(r3a, y2.w, a0[11]); a1[11] = fmaf(r3b, y2.w, a1[11]);
        a0[12] = fmaf(r3a, y3.x, a0[12]); a1[12] = fmaf(r3b, y3.x, a1[12]);
        a0[13] = fmaf(r3a, y3.y, a0[13]); a1[13] = fmaf(r3b, y3.y, a1[13]);
        a0[14] = fmaf(r3a, y3.z, a0[14]); a1[14] = fmaf(r3b, y3.z, a1[14]);
        a0[15] = fmaf(r3a, y3.w, a0[15]); a1[15] = fmaf(r3b, y3.w, a1[15]);
    }

#pragma unroll
    for (int m = 0; m < 16; ++m)
        *reinterpret_cast<float2*>(agg + ((size_t)m * N + n) * 128 + 2 * lane) =
            make_float2(a0[m] * 0.0625f, a1[m] * 0.0625f);
}

// ---------------- phase-B GEMM: Ap[n][m][d] = agg[row][:] @ W_out[l] (n-major out) ----------

__global__ __launch_bounds__(256, 4) void k_gemmB(
    const float* __restrict__ agg, const float* __restrict__ W_out,
    float* __restrict__ Ap, int N)
{
    __shared__ float at[64][132];
    const int tid = threadIdx.x;
    const int r0 = blockIdx.x * 64;
    const int m = r0 / N;
    const int n0 = r0 - m * N;
    const int l = (m == 0) ? 0 : (m < 4) ? 1 : (m < 9) ? 2 : 3;
    const float4* W4 = reinterpret_cast<const float4*>(W_out + (size_t)l * 16384);

    const float4* agg4 = reinterpret_cast<const float4*>(agg + (size_t)r0 * 128);
#pragma unroll
    for (int i = 0; i < 8; ++i) {
        int f = i * 256 + tid;
        int row = f >> 5, c4 = f & 31;
        float4 v = agg4[f];
        *reinterpret_cast<float4*>(&at[row][c4 * 4]) = v;
    }
    __syncthreads();

    const int ct = tid & 31;
    const int rt = tid >> 5;
    float acc[8][4];
#pragma unroll
    for (int i = 0; i < 8; ++i)
#pragma unroll
        for (int j = 0; j < 4; ++j) acc[i][j] = 0.f;

#pragma unroll 2
    for (int k4 = 0; k4 < 32; ++k4) {
        float4 a[8];
#pragma unroll
        for (int i = 0; i < 8; ++i)
            a[i] = *reinterpret_cast<const float4*>(&at[rt * 8 + i][k4 * 4]);
        float4 w[4];
#pragma unroll
        for (int j = 0; j < 4; ++j)
            w[j] = W4[(k4 * 4 + j) * 32 + ct];
#pragma unroll
        for (int i = 0; i < 8; ++i) {
            const float* ai = &a[i].x;
#pragma unroll
            for (int j = 0; j < 4; ++j) {
                const float* wj = &w[j].x;
                float av = ai[j];
                acc[i][0] = fmaf(av, wj[0], acc[i][0]);
                acc[i][1] = fmaf(av, wj[1], acc[i][1]);
                acc[i][2] = fmaf(av, wj[2], acc[i][2]);
                acc[i][3] = fmaf(av, wj[3], acc[i][3]);
            }
        }
    }

    // store n-major: Ap[n][m][d]
#pragma unroll
    for (int i = 0; i < 8; ++i) {
        int n = n0 + rt * 8 + i;
        *reinterpret_cast<float4*>(Ap + (size_t)n * 2048 + m * 128 + ct * 4) =
            make_float4(acc[i][0], acc[i][1], acc[i][2], acc[i][3]);
    }
}

// ---------------- node tail: norms + poly (C) + out GEMM (D); 8 nodes/block ----------------

__global__ __launch_bounds__(256) void k_nodeCD(
    const int* __restrict__ elem, const float* __restrict__ Ap,
    const float* __restrict__ sc0e,
    const float* __restrict__ Wp0, const float* __restrict__ Wp1,
    const float* __restrict__ Wlin0, const float* __restrict__ Wlin1,
    float* __restrict__ out, int N)
{
    __shared__ float p_lds[8][4][132];
    const int tid = threadIdx.x;
    const int nbase = blockIdx.x * 8;

    // ---- phase C ----
    {
        const int d = tid & 127;
        const int hb = tid >> 7;
#pragma unroll
        for (int qq = 0; qq < 4; ++qq) {
            int ni = hb * 4 + qq;
            int n = nbase + ni;
            int a = elem[n];
            const float* ap = Ap + (size_t)n * 2048 + d;
            float Am[16];
#pragma unroll
            for (int m = 0; m < 16; ++m)
                Am[m] = ap[m * 128];
            float s = Am[0];
            float n1 = Am[1] * Am[1] + Am[2] * Am[2] + Am[3] * Am[3];
            float n2 = Am[4] * Am[4] + Am[5] * Am[5] + Am[6] * Am[6] + Am[7] * Am[7] + Am[8] * Am[8];
            float n3 = Am[9] * Am[9] + Am[10] * Am[10] + Am[11] * Am[11] + Am[12] * Am[12] +
                       Am[13] * Am[13] + Am[14] * Am[14] + Am[15] * Am[15];
            float s2 = s * s;
            float B0v[9] = {s, s2, s2 * s, n1, n2, n3, s * n1, s * n2, s * n3};
            const float* wp0 = Wp0 + (size_t)(a * 9) * 128 + d;
            float p0 = 0.f;
#pragma unroll
            for (int b = 0; b < 9; ++b) p0 = fmaf(wp0[b * 128], B0v[b], p0);
            float coefv[6] = {1.0f, s, s2, n1, n2, n3};
            const float* wp1 = Wp1 + (size_t)(a * 6) * 128 + d;
            float q1 = 0.f;
#pragma unroll
            for (int b = 0; b < 6; ++b) q1 = fmaf(wp1[b * 128], coefv[b], q1);
            p_lds[ni][0][d] = p0;
            p_lds[ni][1][d] = Am[1] * q1;
            p_lds[ni][2][d] = Am[2] * q1;
            p_lds[ni][3][d] = Am[3] * q1;
        }
    }
    __syncthreads();

    // ---- phase D: deep unroll so W-loads pipeline (VGPR44 serialization fix) ----
    {
        const int dq2 = tid & 15;
        const int combo = tid >> 4;
        const int row = combo & 3;
        const int dbase = dq2 * 8;
        const float* Wl = (row == 0) ? Wlin0 : Wlin1;

#pragma unroll
        for (int half = 0; half < 2; ++half) {
            const int ni = (combo >> 2) + half * 4;
            const int n = nbase + ni;

            float o[8];
#pragma unroll
            for (int k = 0; k < 8; ++k) o[k] = 0.f;
#pragma unroll 8
            for (int c4 = 0; c4 < 32; ++c4) {
                float4 p4 = *reinterpret_cast<const float4*>(&p_lds[ni][row][c4 * 4]);
                const float* pp = &p4.x;
#pragma unroll
                for (int j = 0; j < 4; ++j) {
                    const float* wr = Wl + (size_t)(c4 * 4 + j) * 128 + dbase;
                    float4 w0 = *reinterpret_cast<const float4*>(wr);
                    float4 w1 = *reinterpret_cast<const float4*>(wr + 4);
                    float pv = pp[j];
                    o[0] = fmaf(pv, w0.x, o[0]); o[1] = fmaf(pv, w0.y, o[1]);
                    o[2] = fmaf(pv, w0.z, o[2]); o[3] = fmaf(pv, w0.w, o[3]);
                    o[4] = fmaf(pv, w1.x, o[4]); o[5] = fmaf(pv, w1.y, o[5]);
                    o[6] = fmaf(pv, w1.z, o[6]); o[7] = fmaf(pv, w1.w, o[7]);
                }
            }
            if (row == 0) {
                const float* sc = sc0e + (size_t)elem[n] * 128 + dbase;
#pragma unroll
                for (int k = 0; k < 8; ++k) o[k] += sc[k];
            }
            float* op = out + (size_t)n * 512 + (size_t)row * 128 + dbase;
            *reinterpret_cast<float4*>(op)     = make_float4(o[0], o[1], o[2], o[3]);
            *reinterpret_cast<float4*>(op + 4) = make_float4(o[4], o[5], o[6], o[7]);
        }
    }
}

// ---------------- launcher ----------------

extern "C" void kernel_launch(void* const* d_in, const int* in_sizes, int n_in,
                              void* d_out, int out_size, void* d_ws, size_t ws_size,
                              hipStream_t stream) {
    const float* x       = (const float*)d_in[0];
    const float* evec    = (const float*)d_in[1];
    const float* elen    = (const float*)d_in[2];
    const int*   eidx    = (const int*)d_in[3];
    const float* W_embed = (const float*)d_in[4];
    const float* W_skip  = (const float*)d_in[5];
    const float* W_up    = (const float*)d_in[6];
    const float* Wr1     = (const float*)d_in[7];
    const float* Wr2     = (const float*)d_in[8];
    const float* Wr3     = (const float*)d_in[9];
    const float* Wr4     = (const float*)d_in[10];
    const float* W_out   = (const float*)d_in[11];
    const float* Wp0     = (const float*)d_in[12];
    const float* Wp1     = (const float*)d_in[13];
    const float* Wlin0   = (const float*)d_in[14];
    const float* Wlin1   = (const float*)d_in[15];
    float* out = (float*)d_out;

    const int N = in_sizes[0] / NELEM;
    const int E = in_sizes[2];

    char* base = (char*)d_ws;
    size_t off = 0;
    auto alloc = [&](size_t b) { size_t o = off; off += (b + 255) & ~(size_t)255; return o; };
    int*   elem  = (int*)(base + alloc((size_t)N * 4));
    float* helem = (float*)(base + alloc((size_t)NELEM * C * 4));
    float* sc0e  = (float*)(base + alloc((size_t)NELEM * C * 4));
    unsigned short* WbT = (unsigned short*)(base + alloc(32768 * 2));
    unsigned short* WbA = (unsigned short*)(base + alloc(8192 * 2));
    int*   deg   = (int*)(base + alloc((size_t)N * 4));
    int*   offs  = (int*)(base + alloc((size_t)(N + 1) * 4));
    int*   cur   = (int*)(base + alloc((size_t)N * 4));
    int*   epos  = (int*)(base + alloc((size_t)E * 4));
    int*   eel   = (int*)(base + alloc((size_t)E * 4));

    // region R: Rw (later reused for Ap)
    size_t szRw = (size_t)E * RWS * 2 + 256;
    size_t szAp = (size_t)N * 16 * 128 * 4;
    size_t offR = alloc(szRw > szAp ? szRw : szAp);
    unsigned short* Rw = (unsigned short*)(base + offR);
    float* Ap = (float*)(base + offR);

    // region S: Yw + T1b + Tb (agg overlays the start after Rw consumed)
    size_t szY = (size_t)E * 16 * 4;
    size_t szT1 = (size_t)E * 64 * 2;
    size_t szTb = (size_t)E * 64 * 2;
    size_t szAgg = (size_t)N * 16 * 128 * 4;
    size_t need = szY + 256 + szT1 + 256 + szTb;
    size_t offS = alloc(need > szAgg ? need : szAgg);
    float* Yw = (float*)(base + offS);
    unsigned short* T1b = (unsigned short*)(base + ((offS + szY + 255) & ~(size_t)255));
    unsigned short* Tb  = (unsigned short*)((char*)T1b + ((szT1 + 255) & ~(size_t)255));
    float* agg = (float*)(base + offS);
    (void)n_in; (void)out_size; (void)ws_size;

    hipMemsetAsync(deg, 0, (size_t)N * 4, stream);
    hipMemsetAsync(cur, 0, (size_t)N * 4, stream);

    k_tables<<<NELEM, 128, 0, stream>>>(W_embed, W_up, W_skip, helem, sc0e);
    k_elem<<<(N + 255) / 256, 256, 0, stream>>>(x, elem, N);
    k_wprep<<<128, 256, 0, stream>>>(Wr4, WbT);
    k_wprep23<<<32, 256, 0, stream>>>(Wr2, Wr3, WbA);
    k_hist<<<(E + 255) / 256, 256, 0, stream>>>(eidx, elem, deg, eel, E);
    k_scan<<<1, 1024, 0, stream>>>(deg, offs, N);
    k_scatter<<<(E + 255) / 256, 256, 0, stream>>>(eidx, offs, cur, epos, E);
    k_edge_pre<<<(E + 255) / 256, 256, 0, stream>>>(evec, elen, Wr1, Yw, T1b, E);
    k_l23m<<<E / 128, 256, 0, stream>>>(T1b, WbA, Tb, E);
    k_l4m<<<E / 128, 256, 0, stream>>>(Tb, WbT, eel, epos, helem, Yw, Rw, E);
    k_agg<<<N / 4, 256, 0, stream>>>(offs, Rw, agg, N);
    k_gemmB<<<(16 * N) / 64, 256, 0, stream>>>(agg, W_out, Ap, N);
    k_nodeCD<<<N / 8, 256, 0, stream>>>(elem, Ap, sc0e, Wp0, Wp1, Wlin0, Wlin1, out, N);
}

// Round 20
// 264.351 us; speedup vs baseline: 1.1613x; 1.1613x over previous
//
#include <hip/hip_runtime.h>

#define NELEM 10
#define C 128
#define RWS 544   // packed row stride in ushorts: 512 bf16 R + 32 ushorts (16 f32) Y

typedef __bf16 bf16x8 __attribute__((ext_vector_type(8)));
typedef float f32x4 __attribute__((ext_vector_type(4)));

__device__ inline unsigned short f2bf(float f) {
    unsigned x = __float_as_uint(f);
    unsigned r = (x + 0x7fffu + ((x >> 16) & 1u)) >> 16;
    return (unsigned short)r;
}
__device__ inline float bf2f(unsigned short b) {
    return __uint_as_float(((unsigned)b) << 16);
}

// ---------------- small prep kernels ----------------

__global__ __launch_bounds__(128) void k_tables(
    const float* __restrict__ W_embed, const float* __restrict__ W_up,
    const float* __restrict__ W_skip,
    float* __restrict__ h_elem, float* __restrict__ sc0e) {
    const int a = blockIdx.x;
    const int c = threadIdx.x;
    float acc = 0.f, acc2 = 0.f;
#pragma unroll 4
    for (int k = 0; k < C; ++k) {
        float we = W_embed[a * C + k];
        acc  = fmaf(we, W_up[k * C + c], acc);
        acc2 = fmaf(we, W_skip[(k * NELEM + a) * C + c], acc2);
    }
    h_elem[a * C + c] = acc;
    sc0e[a * C + c] = acc2;
}

__global__ void k_elem(const float* __restrict__ x, int* __restrict__ elem, int n) {
    int i = blockIdx.x * 256 + threadIdx.x;
    if (i >= n) return;
    int a = 0;
    float best = x[i * NELEM];
    for (int j = 1; j < NELEM; ++j) {
        float v = x[i * NELEM + j];
        if (v > best) { best = v; a = j; }
    }
    elem[i] = a;
}

// pack Wr4 -> MFMA A-fragments (W^T tiles), bf16 (32 ctiles):
__global__ void k_wprep(const float* __restrict__ Wr4, unsigned short* __restrict__ WbT) {
    int idx = blockIdx.x * 256 + threadIdx.x;   // 32768
    int j = idx & 7;
    int l = (idx >> 3) & 63;
    int ks = (idx >> 9) & 1;
    int ctile = idx >> 10;
    int k = ks * 32 + (l >> 4) * 8 + j;
    int c = ctile * 16 + (l & 15);
    WbT[idx] = f2bf(Wr4[k * 512 + c]);
}

// pack Wr2,Wr3 (64x64) -> MFMA A-fragments, bf16 (4 ctiles each)
__global__ void k_wprep23(const float* __restrict__ Wr2, const float* __restrict__ Wr3,
                          unsigned short* __restrict__ WbA) {
    int idx = blockIdx.x * 256 + threadIdx.x;   // 8192
    int which = idx >> 12;
    int r = idx & 4095;
    int j = r & 7;
    int l = (r >> 3) & 63;
    int ks = (r >> 9) & 1;
    int ct = (r >> 10) & 3;
    const float* W = which ? Wr3 : Wr2;
    int k = ks * 32 + (l >> 4) * 8 + j;
    int c = ct * 16 + (l & 15);
    WbA[idx] = f2bf(W[k * 64 + c]);
}

// pack Wlin0,Wlin1 (128x128) -> MFMA A-fragments, bf16 (8 ctiles x 4 ks each)
__global__ void k_wprepL(const float* __restrict__ Wlin0, const float* __restrict__ Wlin1,
                         unsigned short* __restrict__ WlA) {
    int idx = blockIdx.x * 256 + threadIdx.x;   // 32768
    int which = idx >> 14;
    int r = idx & 16383;
    int j = r & 7;
    int l = (r >> 3) & 63;
    int ks = (r >> 9) & 3;
    int ct = r >> 11;
    const float* W = which ? Wlin1 : Wlin0;
    int k = ks * 32 + (l >> 4) * 8 + j;
    int c = ct * 16 + (l & 15);
    WlA[idx] = f2bf(W[k * 128 + c]);
}

// ---------------- CSR build (offsets + inverse permutation + sender element) ----------------

__global__ void k_hist(const int* __restrict__ ei, const int* __restrict__ elem,
                       int* __restrict__ deg, int* __restrict__ eel, int E) {
    int e = blockIdx.x * 256 + threadIdx.x;
    if (e < E) {
        atomicAdd(&deg[ei[E + e]], 1);
        eel[e] = elem[ei[e]];
    }
}

__global__ void k_scan(const int* __restrict__ deg, int* __restrict__ offs, int n) {
    __shared__ int sums[1024];
    int tid = threadIdx.x;
    int base = tid * 8;
    int loc[8];
    int s = 0;
#pragma unroll
    for (int i = 0; i < 8; ++i) {
        loc[i] = s;
        if (base + i < n) s += deg[base + i];
    }
    sums[tid] = s;
    __syncthreads();
    for (int st = 1; st < 1024; st <<= 1) {
        int v = 0;
        if (tid >= st) v = sums[tid - st];
        __syncthreads();
        sums[tid] += v;
        __syncthreads();
    }
    int excl = sums[tid] - s;
#pragma unroll
    for (int i = 0; i < 8; ++i)
        if (base + i < n) offs[base + i] = excl + loc[i];
    if (tid == 1023) offs[n] = sums[1023];
}

__global__ void k_scatter(const int* __restrict__ ei, const int* __restrict__ offs,
                          int* __restrict__ cur, int* __restrict__ epos, int E) {
    int e = blockIdx.x * 256 + threadIdx.x;
    if (e < E) {
        int r = ei[E + e];
        int p = atomicAdd(&cur[r], 1);
        epos[e] = offs[r] + p;
    }
}

// ---------------- edge pre-kernel: Y + radial + layer 1 only ----------------

__global__ __launch_bounds__(256, 2) void k_edge_pre(
    const float* __restrict__ evec, const float* __restrict__ elen,
    const float* __restrict__ Wr1,
    float* __restrict__ Yw, unsigned short* __restrict__ T1b, int E)
{
    const int tid = threadIdx.x;
    const int e = blockIdx.x * 256 + tid;
    if (e >= E) return;

    float vx = evec[3 * e], vy = evec[3 * e + 1], vz = evec[3 * e + 2];
    float inv = rsqrtf(vx * vx + vy * vy + vz * vz);
    float ux = vx * inv, uy = vy * inv, uz = vz * inv;

    const float s3    = 1.7320508075688772f;
    const float s5h   = 1.118033988749895f;
    const float s15   = 3.872983346207417f;
    const float s15h  = 1.9364916731037085f;
    const float s70_4 = 2.091650066335189f;
    const float s105  = 10.246950765959598f;
    const float s105_2= 5.123475382979799f;
    const float s42_4 = 1.6201851746019651f;
    const float s7_2  = 1.3228756555322954f;

    float xx = ux * ux, yy = uy * uy, zz = uz * uz;
    float4* yo = reinterpret_cast<float4*>(Yw + ((size_t)e << 4));
    yo[0] = make_float4(1.0f, s3 * ux, s3 * uy, s3 * uz);
    yo[1] = make_float4(s15 * ux * uy, s15 * uy * uz, s5h * (3.0f * zz - 1.0f), s15 * ux * uz);
    yo[2] = make_float4(s15h * (xx - yy),
                        s70_4 * uy * (3.0f * xx - yy),
                        s105 * ux * uy * uz,
                        s42_4 * uy * (5.0f * zz - 1.0f));
    yo[3] = make_float4(s7_2 * uz * (5.0f * zz - 3.0f),
                        s42_4 * ux * (5.0f * zz - 1.0f),
                        s105_2 * uz * (xx - yy),
                        s70_4 * ux * (xx - 3.0f * yy));

    float r = elen[e];
    float u = r * 0.2f;
    float u2 = u * u;
    float u5 = u2 * u2 * u;
    float env = 1.0f - 21.0f * u5 + 35.0f * u5 * u - 15.0f * u5 * u2;
    if (u >= 1.0f) env = 0.0f;
    float th = 3.14159265358979323846f * u;
    float s1 = __sinf(th), c1 = __cosf(th);
    float pref = 0.6324555320336759f * env / r;
    float ef[8];
    float sn = s1, cn = c1;
    ef[0] = pref * sn;
#pragma unroll
    for (int nn = 1; nn < 8; ++nn) {
        float sn1 = sn * c1 + cn * s1;
        float cn1 = cn * c1 - sn * s1;
        sn = sn1; cn = cn1;
        ef[nn] = pref * sn;
    }

    // layer 1: 8 -> 64 + silu
    float t[64];
#pragma unroll
    for (int j = 0; j < 64; ++j) t[j] = 0.0f;
#pragma unroll
    for (int i = 0; i < 8; ++i) {
        const float4* w1r = reinterpret_cast<const float4*>(Wr1 + i * 64);
        float efi = ef[i];
#pragma unroll
        for (int j4 = 0; j4 < 16; ++j4) {
            float4 w = w1r[j4];
            t[4 * j4 + 0] = fmaf(efi, w.x, t[4 * j4 + 0]);
            t[4 * j4 + 1] = fmaf(efi, w.y, t[4 * j4 + 1]);
            t[4 * j4 + 2] = fmaf(efi, w.z, t[4 * j4 + 2]);
            t[4 * j4 + 3] = fmaf(efi, w.w, t[4 * j4 + 3]);
        }
    }
#pragma unroll
    for (int j = 0; j < 64; ++j) {
        float v = t[j];
        t[j] = v * __builtin_amdgcn_rcpf(1.0f + __expf(-v));
    }

    // store T1 as MFMA B-fragments
    {
        const int etile = e >> 4, cc = e & 15;
#pragma unroll
        for (int ks = 0; ks < 2; ++ks) {
#pragma unroll
            for (int q = 0; q < 4; ++q) {
                const float* tp = &t[ks * 32 + q * 8];
                unsigned d0 = (unsigned)f2bf(tp[0]) | ((unsigned)f2bf(tp[1]) << 16);
                unsigned d1 = (unsigned)f2bf(tp[2]) | ((unsigned)f2bf(tp[3]) << 16);
                unsigned d2 = (unsigned)f2bf(tp[4]) | ((unsigned)f2bf(tp[5]) << 16);
                unsigned d3 = (unsigned)f2bf(tp[6]) | ((unsigned)f2bf(tp[7]) << 16);
                *reinterpret_cast<uint4*>(
                    T1b + (((size_t)(etile * 2 + ks) * 64) + q * 16 + cc) * 8) =
                    make_uint4(d0, d1, d2, d3);
            }
        }
    }
}

// ---------------- layers 2+3 via MFMA ----------------

__global__ __launch_bounds__(256) void k_l23m(
    const unsigned short* __restrict__ T1b, const unsigned short* __restrict__ WbA,
    unsigned short* __restrict__ Tb, int E)
{
    __shared__ unsigned short lb[4][32][72];
    const int lane = threadIdx.x & 63;
    const int wv = threadIdx.x >> 6;
    const int ebase = blockIdx.x * 128 + wv * 32;
    const int et0 = ebase >> 4;
    const int g = lane >> 4;
    const int rr = lane & 15;

    bf16x8 bt[2][2];
#pragma unroll
    for (int et = 0; et < 2; ++et)
#pragma unroll
        for (int ks = 0; ks < 2; ++ks)
            bt[et][ks] = *reinterpret_cast<const bf16x8*>(
                T1b + (((size_t)(et0 + et) * 2 + ks) * 64 + lane) * 8);

    const unsigned short* WA2 = WbA;
    const unsigned short* WA3 = WbA + 4096;
#pragma unroll
    for (int ct = 0; ct < 4; ++ct) {
        bf16x8 a0 = *reinterpret_cast<const bf16x8*>(WA2 + (((size_t)ct * 2 + 0) * 64 + lane) * 8);
        bf16x8 a1 = *reinterpret_cast<const bf16x8*>(WA2 + (((size_t)ct * 2 + 1) * 64 + lane) * 8);
#pragma unroll
        for (int et = 0; et < 2; ++et) {
            f32x4 acc = {0.f, 0.f, 0.f, 0.f};
            acc = __builtin_amdgcn_mfma_f32_16x16x32_bf16(a0, bt[et][0], acc, 0, 0, 0);
            acc = __builtin_amdgcn_mfma_f32_16x16x32_bf16(a1, bt[et][1], acc, 0, 0, 0);
            float v0 = acc[0] * __builtin_amdgcn_rcpf(1.0f + __expf(-acc[0]));
            float v1 = acc[1] * __builtin_amdgcn_rcpf(1.0f + __expf(-acc[1]));
            float v2 = acc[2] * __builtin_amdgcn_rcpf(1.0f + __expf(-acc[2]));
            float v3 = acc[3] * __builtin_amdgcn_rcpf(1.0f + __expf(-acc[3]));
            unsigned p0 = (unsigned)f2bf(v0) | ((unsigned)f2bf(v1) << 16);
            unsigned p1 = (unsigned)f2bf(v2) | ((unsigned)f2bf(v3) << 16);
            *reinterpret_cast<uint2*>(&lb[wv][et * 16 + rr][ct * 16 + g * 4]) =
                make_uint2(p0, p1);
        }
    }
    asm volatile("s_waitcnt lgkmcnt(0)" ::: "memory");
    __builtin_amdgcn_sched_barrier(0);

    bf16x8 bt2[2][2];
#pragma unroll
    for (int et = 0; et < 2; ++et)
#pragma unroll
        for (int ks = 0; ks < 2; ++ks)
            bt2[et][ks] = *reinterpret_cast<const bf16x8*>(
                &lb[wv][et * 16 + rr][ks * 32 + g * 8]);

#pragma unroll
    for (int ct = 0; ct < 4; ++ct) {
        bf16x8 a0 = *reinterpret_cast<const bf16x8*>(WA3 + (((size_t)ct * 2 + 0) * 64 + lane) * 8);
        bf16x8 a1 = *reinterpret_cast<const bf16x8*>(WA3 + (((size_t)ct * 2 + 1) * 64 + lane) * 8);
        int c0 = ct * 16 + g * 4;
        int ks3 = c0 >> 5;
        int q3 = (c0 >> 3) & 3;
        int joff = c0 & 7;
#pragma unroll
        for (int et = 0; et < 2; ++et) {
            f32x4 acc = {0.f, 0.f, 0.f, 0.f};
            acc = __builtin_amdgcn_mfma_f32_16x16x32_bf16(a0, bt2[et][0], acc, 0, 0, 0);
            acc = __builtin_amdgcn_mfma_f32_16x16x32_bf16(a1, bt2[et][1], acc, 0, 0, 0);
            float v0 = acc[0] * __builtin_amdgcn_rcpf(1.0f + __expf(-acc[0]));
            float v1 = acc[1] * __builtin_amdgcn_rcpf(1.0f + __expf(-acc[1]));
            float v2 = acc[2] * __builtin_amdgcn_rcpf(1.0f + __expf(-acc[2]));
            float v3 = acc[3] * __builtin_amdgcn_rcpf(1.0f + __expf(-acc[3]));
            unsigned p0 = (unsigned)f2bf(v0) | ((unsigned)f2bf(v1) << 16);
            unsigned p1 = (unsigned)f2bf(v2) | ((unsigned)f2bf(v3) << 16);
            *reinterpret_cast<uint2*>(
                Tb + (((size_t)(et0 + et) * 2 + ks3) * 64 + q3 * 16 + rr) * 8 + joff) =
                make_uint2(p0, p1);
        }
    }
}

// ---------------- layer-4 via MFMA ----------------

__global__ __launch_bounds__(256) void k_l4m(
    const unsigned short* __restrict__ Tb, const unsigned short* __restrict__ WbT,
    const int* __restrict__ eel, const int* __restrict__ epos,
    const float* __restrict__ h_elem, const float* __restrict__ Yw,
    unsigned short* __restrict__ Rw, int E)
{
    const int lane = threadIdx.x & 63;
    const int wv = threadIdx.x >> 6;
    const int ebase = blockIdx.x * 128 + wv * 32;
    const int et0 = ebase >> 4;

    bf16x8 bt[2][2];
#pragma unroll
    for (int et = 0; et < 2; ++et)
#pragma unroll
        for (int ks = 0; ks < 2; ++ks)
            bt[et][ks] = *reinterpret_cast<const bf16x8*>(
                Tb + (((size_t)(et0 + et) * 2 + ks) * 64 + lane) * 8);

    int a_[2], pe_[2];
#pragma unroll
    for (int et = 0; et < 2; ++et) {
        int e = ebase + et * 16 + (lane & 15);
        a_[et] = eel[e];
        pe_[et] = epos[e];
    }
    const int crow = (lane >> 4) * 4;

#pragma unroll 2
    for (int ctile = 0; ctile < 32; ++ctile) {
        bf16x8 aw0 = *reinterpret_cast<const bf16x8*>(
            WbT + (((size_t)ctile * 2 + 0) * 64 + lane) * 8);
        bf16x8 aw1 = *reinterpret_cast<const bf16x8*>(
            WbT + (((size_t)ctile * 2 + 1) * 64 + lane) * 8);
        int cb = ctile * 16 + crow;
        int ch = cb & 127;
#pragma unroll
        for (int et = 0; et < 2; ++et) {
            f32x4 acc = {0.f, 0.f, 0.f, 0.f};
            acc = __builtin_amdgcn_mfma_f32_16x16x32_bf16(aw0, bt[et][0], acc, 0, 0, 0);
            acc = __builtin_amdgcn_mfma_f32_16x16x32_bf16(aw1, bt[et][1], acc, 0, 0, 0);
            float4 h = *reinterpret_cast<const float4*>(h_elem + a_[et] * 128 + ch);
            float v0 = acc[0] * h.x, v1 = acc[1] * h.y;
            float v2 = acc[2] * h.z, v3 = acc[3] * h.w;
            unsigned p0 = (unsigned)f2bf(v0) | ((unsigned)f2bf(v1) << 16);
            unsigned p1 = (unsigned)f2bf(v2) | ((unsigned)f2bf(v3) << 16);
            *reinterpret_cast<uint2*>(Rw + (size_t)pe_[et] * RWS + cb) = make_uint2(p0, p1);
        }
    }

#pragma unroll
    for (int it = 0; it < 2; ++it) {
        int task = it * 64 + lane;
        int eo = task >> 2, sub = task & 3;
        int e = ebase + eo;
        int pe = epos[e];
        float4 y = *reinterpret_cast<const float4*>(Yw + ((size_t)e << 4) + sub * 4);
        *reinterpret_cast<float4*>(Rw + (size_t)pe * RWS + 512 + sub * 8) = y;
    }
}

// ---------------- gather: wave per node, NO LDS, NO barriers; m-major output ----------------

__global__ __launch_bounds__(256, 6) void k_agg(
    const int* __restrict__ offs, const unsigned short* __restrict__ Rw,
    float* __restrict__ agg, int N)
{
    const int lane = threadIdx.x & 63;
    const int wv = threadIdx.x >> 6;
    const int n = blockIdx.x * 4 + wv;
    const int beg = offs[n], end = offs[n + 1];

    float a0[16], a1[16];
#pragma unroll
    for (int m = 0; m < 16; ++m) { a0[m] = 0.f; a1[m] = 0.f; }

#pragma unroll 4
    for (int k = beg; k < end; ++k) {
        const unsigned short* row = Rw + (size_t)k * RWS;
        const ushort2* rw = reinterpret_cast<const ushort2*>(row);
        ushort2 r0 = rw[lane];
        ushort2 r1 = rw[64 + lane];
        ushort2 r2 = rw[128 + lane];
        ushort2 r3 = rw[192 + lane];
        const float4* Y4 = reinterpret_cast<const float4*>(row + 512);
        float4 y0 = Y4[0], y1 = Y4[1], y2 = Y4[2], y3 = Y4[3];
        float r0a = bf2f(r0.x), r0b = bf2f(r0.y);
        float r1a = bf2f(r1.x), r1b = bf2f(r1.y);
        float r2a = bf2f(r2.x), r2b = bf2f(r2.y);
        float r3a = bf2f(r3.x), r3b = bf2f(r3.y);
        a0[0]  = fmaf(r0a, y0.x, a0[0]);  a1[0]  = fmaf(r0b, y0.x, a1[0]);
        a0[1]  = fmaf(r1a, y0.y, a0[1]);  a1[1]  = fmaf(r1b, y0.y, a1[1]);
        a0[2]  = fmaf(r1a, y0.z, a0[2]);  a1[2]  = fmaf(r1b, y0.z, a1[2]);
        a0[3]  = fmaf(r1a, y0.w, a0[3]);  a1[3]  = fmaf(r1b, y0.w, a1[3]);
        a0[4]  = fmaf(r2a, y1.x, a0[4]);  a1[4]  = fmaf(r2b, y1.x, a1[4]);
        a0[5]  = fmaf(r2a, y1.y, a0[5]);  a1[5]  = fmaf(r2b, y1.y, a1[5]);
        a0[6]  = fmaf(r2a, y1.z, a0[6]);  a1[6]  = fmaf(r2b, y1.z, a1[6]);
        a0[7]  = fmaf(r2a, y1.w, a0[7]);  a1[7]  = fmaf(r2b, y1.w, a1[7]);
        a0[8]  = fmaf(r2a, y2.x, a0[8]);  a1[8]  = fmaf(r2b, y2.x, a1[8]);
        a0[9]  = fmaf(r3a, y2.y, a0[9]);  a1[9]  = fmaf(r3b, y2.y, a1[9]);
        a0[10] = fmaf(r3a, y2.z, a0[10]); a1[10] = fmaf(r3b, y2.z, a1[10]);
        a0[11] = fmaf(r3a, y2.w, a0[11]); a1[11] = fmaf(r3b, y2.w, a1[11]);
        a0[12] = fmaf(r3a, y3.x, a0[12]); a1[12] = fmaf(r3b, y3.x, a1[12]);
        a0[13] = fmaf(r3a, y3.y, a0[13]); a1[13] = fmaf(r3b, y3.y, a1[13]);
        a0[14] = fmaf(r3a, y3.z, a0[14]); a1[14] = fmaf(r3b, y3.z, a1[14]);
        a0[15] = fmaf(r3a, y3.w, a0[15]); a1[15] = fmaf(r3b, y3.w, a1[15]);
    }

#pragma unroll
    for (int m = 0; m < 16; ++m)
        *reinterpret_cast<float2*>(agg + ((size_t)m * N + n) * 128 + 2 * lane) =
            make_float2(a0[m] * 0.0625f, a1[m] * 0.0625f);
}

// ---------------- phase-B GEMM: Ap[n][m][d] = agg[row][:] @ W_out[l] (n-major out) ----------

__global__ __launch_bounds__(256, 4) void k_gemmB(
    const float* __restrict__ agg, const float* __restrict__ W_out,
    float* __restrict__ Ap, int N)
{
    __shared__ float at[64][132];
    const int tid = threadIdx.x;
    const int r0 = blockIdx.x * 64;
    const int m = r0 / N;
    const int n0 = r0 - m * N;
    const int l = (m == 0) ? 0 : (m < 4) ? 1 : (m < 9) ? 2 : 3;
    const float4* W4 = reinterpret_cast<const float4*>(W_out + (size_t)l * 16384);

    const float4* agg4 = reinterpret_cast<const float4*>(agg + (size_t)r0 * 128);
#pragma unroll
    for (int i = 0; i < 8; ++i) {
        int f = i * 256 + tid;
        int row = f >> 5, c4 = f & 31;
        float4 v = agg4[f];
        *reinterpret_cast<float4*>(&at[row][c4 * 4]) = v;
    }
    __syncthreads();

    const int ct = tid & 31;
    const int rt = tid >> 5;
    float acc[8][4];
#pragma unroll
    for (int i = 0; i < 8; ++i)
#pragma unroll
        for (int j = 0; j < 4; ++j) acc[i][j] = 0.f;

#pragma unroll 2
    for (int k4 = 0; k4 < 32; ++k4) {
        float4 a[8];
#pragma unroll
        for (int i = 0; i < 8; ++i)
            a[i] = *reinterpret_cast<const float4*>(&at[rt * 8 + i][k4 * 4]);
        float4 w[4];
#pragma unroll
        for (int j = 0; j < 4; ++j)
            w[j] = W4[(k4 * 4 + j) * 32 + ct];
#pragma unroll
        for (int i = 0; i < 8; ++i) {
            const float* ai = &a[i].x;
#pragma unroll
            for (int j = 0; j < 4; ++j) {
                const float* wj = &w[j].x;
                float av = ai[j];
                acc[i][0] = fmaf(av, wj[0], acc[i][0]);
                acc[i][1] = fmaf(av, wj[1], acc[i][1]);
                acc[i][2] = fmaf(av, wj[2], acc[i][2]);
                acc[i][3] = fmaf(av, wj[3], acc[i][3]);
            }
        }
    }

    // store n-major: Ap[n][m][d]
#pragma unroll
    for (int i = 0; i < 8; ++i) {
        int n = n0 + rt * 8 + i;
        *reinterpret_cast<float4*>(Ap + (size_t)n * 2048 + m * 128 + ct * 4) =
            make_float4(acc[i][0], acc[i][1], acc[i][2], acc[i][3]);
    }
}

// ---------------- node phase C: norms + poly; packs P as bf16 MFMA B-fragments ----------------
// 8 nodes/block. Pb0 rows = node n (p0); Pb1 rows = n*3 + (r-1) (A1*q1 rows).

__global__ __launch_bounds__(256) void k_nodeC(
    const int* __restrict__ elem, const float* __restrict__ Ap,
    const float* __restrict__ Wp0, const float* __restrict__ Wp1,
    unsigned short* __restrict__ Pb0, unsigned short* __restrict__ Pb1, int N)
{
    __shared__ float p_lds[8][4][132];
    const int tid = threadIdx.x;
    const int nbase = blockIdx.x * 8;

    {
        const int d = tid & 127;
        const int hb = tid >> 7;
#pragma unroll
        for (int qq = 0; qq < 4; ++qq) {
            int ni = hb * 4 + qq;
            int n = nbase + ni;
            int a = elem[n];
            const float* ap = Ap + (size_t)n * 2048 + d;
            float Am[16];
#pragma unroll
            for (int m = 0; m < 16; ++m)
                Am[m] = ap[m * 128];
            float s = Am[0];
            float n1 = Am[1] * Am[1] + Am[2] * Am[2] + Am[3] * Am[3];
            float n2 = Am[4] * Am[4] + Am[5] * Am[5] + Am[6] * Am[6] + Am[7] * Am[7] + Am[8] * Am[8];
            float n3 = Am[9] * Am[9] + Am[10] * Am[10] + Am[11] * Am[11] + Am[12] * Am[12] +
                       Am[13] * Am[13] + Am[14] * Am[14] + Am[15] * Am[15];
            float s2 = s * s;
            float B0v[9] = {s, s2, s2 * s, n1, n2, n3, s * n1, s * n2, s * n3};
            const float* wp0 = Wp0 + (size_t)(a * 9) * 128 + d;
            float p0 = 0.f;
#pragma unroll
            for (int b = 0; b < 9; ++b) p0 = fmaf(wp0[b * 128], B0v[b], p0);
            float coefv[6] = {1.0f, s, s2, n1, n2, n3};
            const float* wp1 = Wp1 + (size_t)(a * 6) * 128 + d;
            float q1 = 0.f;
#pragma unroll
            for (int b = 0; b < 6; ++b) q1 = fmaf(wp1[b * 128], coefv[b], q1);
            p_lds[ni][0][d] = p0;
            p_lds[ni][1][d] = Am[1] * q1;
            p_lds[ni][2][d] = Am[2] * q1;
            p_lds[ni][3][d] = Am[3] * q1;
        }
    }
    __syncthreads();

    // pack Pb0: 8 rows x 16 chunks = 128 tasks
    if (tid < 128) {
        int rl = tid >> 4;
        int cb8 = (tid & 15) * 8;
        int ks = cb8 >> 5;
        int g = (cb8 >> 3) & 3;
        int grow = nbase + rl;
        int rt = grow >> 4, rr = grow & 15;
        const float* pp = &p_lds[rl][0][cb8];
        unsigned d0 = (unsigned)f2bf(pp[0]) | ((unsigned)f2bf(pp[1]) << 16);
        unsigned d1 = (unsigned)f2bf(pp[2]) | ((unsigned)f2bf(pp[3]) << 16);
        unsigned d2 = (unsigned)f2bf(pp[4]) | ((unsigned)f2bf(pp[5]) << 16);
        unsigned d3 = (unsigned)f2bf(pp[6]) | ((unsigned)f2bf(pp[7]) << 16);
        *reinterpret_cast<uint4*>(Pb0 + ((size_t)(rt * 4 + ks) * 64 + g * 16 + rr) * 8) =
            make_uint4(d0, d1, d2, d3);
    }
    // pack Pb1: 24 rows x 16 chunks = 384 tasks
#pragma unroll
    for (int it = 0; it < 2; ++it) {
        int task = it * 256 + tid;
        if (task < 384) {
            int rl = task >> 4;             // 0..23
            int cb8 = (task & 15) * 8;
            int ks = cb8 >> 5;
            int g = (cb8 >> 3) & 3;
            int nl = rl / 3;
            int rq = rl - nl * 3 + 1;
            int grow = nbase * 3 + rl;
            int rt = grow >> 4, rr = grow & 15;
            const float* pp = &p_lds[nl][rq][cb8];
            unsigned d0 = (unsigned)f2bf(pp[0]) | ((unsigned)f2bf(pp[1]) << 16);
            unsigned d1 = (unsigned)f2bf(pp[2]) | ((unsigned)f2bf(pp[3]) << 16);
            unsigned d2 = (unsigned)f2bf(pp[4]) | ((unsigned)f2bf(pp[5]) << 16);
            unsigned d3 = (unsigned)f2bf(pp[6]) | ((unsigned)f2bf(pp[7]) << 16);
            *reinterpret_cast<uint4*>(Pb1 + ((size_t)(rt * 4 + ks) * 64 + g * 16 + rr) * 8) =
                make_uint4(d0, d1, d2, d3);
        }
    }
}

// ---------------- node phase D via MFMA: out rows = P @ Wlin (+sc0 row0) ----------------
// wave = 32 rows x 128 cols; bid < N/128 -> GEMM1 (Pb0,Wlin0,+sc0), else GEMM2 (Pb1,Wlin1).

__global__ __launch_bounds__(256) void k_nodeD(
    const unsigned short* __restrict__ Pb0, const unsigned short* __restrict__ Pb1,
    const unsigned short* __restrict__ WlA,
    const int* __restrict__ elem, const float* __restrict__ sc0e,
    float* __restrict__ out, int N)
{
    const int lane = threadIdx.x & 63;
    const int wv = threadIdx.x >> 6;
    const int bid = blockIdx.x;
    const int nb1 = N / 128;
    const bool g1 = bid < nb1;
    const unsigned short* Pb = g1 ? Pb0 : Pb1;
    const unsigned short* WA = g1 ? WlA : (WlA + 16384);
    const int rowbase = (g1 ? bid : (bid - nb1)) * 128 + wv * 32;
    const int rt0 = rowbase >> 4;

    bf16x8 bt[2][4];
#pragma unroll
    for (int et = 0; et < 2; ++et)
#pragma unroll
        for (int ks = 0; ks < 4; ++ks)
            bt[et][ks] = *reinterpret_cast<const bf16x8*>(
                Pb + (((size_t)(rt0 + et) * 4 + ks) * 64 + lane) * 8);

    int n_[2], r_[2], a_[2];
#pragma unroll
    for (int et = 0; et < 2; ++et) {
        int grow = rowbase + et * 16 + (lane & 15);
        if (g1) { n_[et] = grow; r_[et] = 0; a_[et] = elem[grow]; }
        else    { n_[et] = grow / 3; r_[et] = grow - n_[et] * 3 + 1; a_[et] = 0; }
    }
    const int crow = (lane >> 4) * 4;

#pragma unroll 2
    for (int ct = 0; ct < 8; ++ct) {
        bf16x8 a0 = *reinterpret_cast<const bf16x8*>(WA + (((size_t)ct * 4 + 0) * 64 + lane) * 8);
        bf16x8 a1 = *reinterpret_cast<const bf16x8*>(WA + (((size_t)ct * 4 + 1) * 64 + lane) * 8);
        bf16x8 a2 = *reinterpret_cast<const bf16x8*>(WA + (((size_t)ct * 4 + 2) * 64 + lane) * 8);
        bf16x8 a3 = *reinterpret_cast<const bf16x8*>(WA + (((size_t)ct * 4 + 3) * 64 + lane) * 8);
        int cb = ct * 16 + crow;
#pragma unroll
        for (int et = 0; et < 2; ++et) {
            f32x4 acc = {0.f, 0.f, 0.f, 0.f};
            acc = __builtin_amdgcn_mfma_f32_16x16x32_bf16(a0, bt[et][0], acc, 0, 0, 0);
            acc = __builtin_amdgcn_mfma_f32_16x16x32_bf16(a1, bt[et][1], acc, 0, 0, 0);
            acc = __builtin_amdgcn_mfma_f32_16x16x32_bf16(a2, bt[et][2], acc, 0, 0, 0);
            acc = __builtin_amdgcn_mfma_f32_16x16x32_bf16(a3, bt[et][3], acc, 0, 0, 0);
            float4 o = make_float4(acc[0], acc[1], acc[2], acc[3]);
            if (g1) {
                float4 sc = *reinterpret_cast<const float4*>(sc0e + (size_t)a_[et] * 128 + cb);
                o.x += sc.x; o.y += sc.y; o.z += sc.z; o.w += sc.w;
            }
            *reinterpret_cast<float4*>(
                out + (size_t)n_[et] * 512 + (size_t)r_[et] * 128 + cb) = o;
        }
    }
}

// ---------------- launcher ----------------

extern "C" void kernel_launch(void* const* d_in, const int* in_sizes, int n_in,
                              void* d_out, int out_size, void* d_ws, size_t ws_size,
                              hipStream_t stream) {
    const float* x       = (const float*)d_in[0];
    const float* evec    = (const float*)d_in[1];
    const float* elen    = (const float*)d_in[2];
    const int*   eidx    = (const int*)d_in[3];
    const float* W_embed = (const float*)d_in[4];
    const float* W_skip  = (const float*)d_in[5];
    const float* W_up    = (const float*)d_in[6];
    const float* Wr1     = (const float*)d_in[7];
    const float* Wr2     = (const float*)d_in[8];
    const float* Wr3     = (const float*)d_in[9];
    const float* Wr4     = (const float*)d_in[10];
    const float* W_out   = (const float*)d_in[11];
    const float* Wp0     = (const float*)d_in[12];
    const float* Wp1     = (const float*)d_in[13];
    const float* Wlin0   = (const float*)d_in[14];
    const float* Wlin1   = (const float*)d_in[15];
    float* out = (float*)d_out;

    const int N = in_sizes[0] / NELEM;
    const int E = in_sizes[2];

    char* base = (char*)d_ws;
    size_t off = 0;
    auto alloc = [&](size_t b) { size_t o = off; off += (b + 255) & ~(size_t)255; return o; };
    int*   elem  = (int*)(base + alloc((size_t)N * 4));
    float* helem = (float*)(base + alloc((size_t)NELEM * C * 4));
    float* sc0e  = (float*)(base + alloc((size_t)NELEM * C * 4));
    unsigned short* WbT = (unsigned short*)(base + alloc(32768 * 2));
    unsigned short* WbA = (unsigned short*)(base + alloc(8192 * 2));
    unsigned short* WlA = (unsigned short*)(base + alloc(32768 * 2));
    int*   deg   = (int*)(base + alloc((size_t)N * 4));
    int*   offs  = (int*)(base + alloc((size_t)(N + 1) * 4));
    int*   cur   = (int*)(base + alloc((size_t)N * 4));
    int*   epos  = (int*)(base + alloc((size_t)E * 4));
    int*   eel   = (int*)(base + alloc((size_t)E * 4));
    unsigned short* Pb0 = (unsigned short*)(base + alloc((size_t)N * 128 * 2));
    unsigned short* Pb1 = (unsigned short*)(base + alloc((size_t)N * 3 * 128 * 2));

    // region R: Rw (later reused for Ap)
    size_t szRw = (size_t)E * RWS * 2 + 256;
    size_t szAp = (size_t)N * 16 * 128 * 4;
    size_t offR = alloc(szRw > szAp ? szRw : szAp);
    unsigned short* Rw = (unsigned short*)(base + offR);
    float* Ap = (float*)(base + offR);

    // region S: Yw + T1b + Tb (agg overlays the start after Rw consumed)
    size_t szY = (size_t)E * 16 * 4;
    size_t szT1 = (size_t)E * 64 * 2;
    size_t szTb = (size_t)E * 64 * 2;
    size_t szAgg = (size_t)N * 16 * 128 * 4;
    size_t need = szY + 256 + szT1 + 256 + szTb;
    size_t offS = alloc(need > szAgg ? need : szAgg);
    float* Yw = (float*)(base + offS);
    unsigned short* T1b = (unsigned short*)(base + ((offS + szY + 255) & ~(size_t)255));
    unsigned short* Tb  = (unsigned short*)((char*)T1b + ((szT1 + 255) & ~(size_t)255));
    float* agg = (float*)(base + offS);
    (void)n_in; (void)out_size; (void)ws_size;

    hipMemsetAsync(deg, 0, (size_t)N * 4, stream);
    hipMemsetAsync(cur, 0, (size_t)N * 4, stream);

    k_tables<<<NELEM, 128, 0, stream>>>(W_embed, W_up, W_skip, helem, sc0e);
    k_elem<<<(N + 255) / 256, 256, 0, stream>>>(x, elem, N);
    k_wprep<<<128, 256, 0, stream>>>(Wr4, WbT);
    k_wprep23<<<32, 256, 0, stream>>>(Wr2, Wr3, WbA);
    k_wprepL<<<128, 256, 0, stream>>>(Wlin0, Wlin1, WlA);
    k_hist<<<(E + 255) / 256, 256, 0, stream>>>(eidx, elem, deg, eel, E);
    k_scan<<<1, 1024, 0, stream>>>(deg, offs, N);
    k_scatter<<<(E + 255) / 256, 256, 0, stream>>>(eidx, offs, cur, epos, E);
    k_edge_pre<<<(E + 255) / 256, 256, 0, stream>>>(evec, elen, Wr1, Yw, T1b, E);
    k_l23m<<<E / 128, 256, 0, stream>>>(T1b, WbA, Tb, E);
    k_l4m<<<E / 128, 256, 0, stream>>>(Tb, WbT, eel, epos, helem, Yw, Rw, E);
    k_agg<<<N / 4, 256, 0, stream>>>(offs, Rw, agg, N);
    k_gemmB<<<(16 * N) / 64, 256, 0, stream>>>(agg, W_out, Ap, N);
    k_nodeC<<<N / 8, 256, 0, stream>>>(elem, Ap, Wp0, Wp1, Pb0, Pb1, N);
    k_nodeD<<<(N / 128) * 4, 256, 0, stream>>>(Pb0, Pb1, WlA, elem, sc0e, out, N);
}

// Round 21
// 237.181 us; speedup vs baseline: 1.2943x; 1.1146x over previous
//
#include <hip/hip_runtime.h>

#define NELEM 10
#define C 128
#define RWS 544   // packed row stride in ushorts: 512 bf16 R + 32 ushorts (16 f32) Y

typedef __bf16 bf16x8 __attribute__((ext_vector_type(8)));
typedef float f32x4 __attribute__((ext_vector_type(4)));

__device__ inline unsigned short f2bf(float f) {
    unsigned x = __float_as_uint(f);
    unsigned r = (x + 0x7fffu + ((x >> 16) & 1u)) >> 16;
    return (unsigned short)r;
}
__device__ inline float bf2f(unsigned short b) {
    return __uint_as_float(((unsigned)b) << 16);
}

// ---------------- small prep kernels ----------------

__global__ __launch_bounds__(128) void k_tables(
    const float* __restrict__ W_embed, const float* __restrict__ W_up,
    const float* __restrict__ W_skip,
    float* __restrict__ h_elem, float* __restrict__ sc0e) {
    const int a = blockIdx.x;
    const int c = threadIdx.x;
    float acc = 0.f, acc2 = 0.f;
#pragma unroll 4
    for (int k = 0; k < C; ++k) {
        float we = W_embed[a * C + k];
        acc  = fmaf(we, W_up[k * C + c], acc);
        acc2 = fmaf(we, W_skip[(k * NELEM + a) * C + c], acc2);
    }
    h_elem[a * C + c] = acc;
    sc0e[a * C + c] = acc2;
}

__global__ void k_elem(const float* __restrict__ x, int* __restrict__ elem, int n) {
    int i = blockIdx.x * 256 + threadIdx.x;
    if (i >= n) return;
    int a = 0;
    float best = x[i * NELEM];
    for (int j = 1; j < NELEM; ++j) {
        float v = x[i * NELEM + j];
        if (v > best) { best = v; a = j; }
    }
    elem[i] = a;
}

// pack Wr4 -> MFMA A-fragments (W^T tiles), bf16 (32 ctiles):
__global__ void k_wprep(const float* __restrict__ Wr4, unsigned short* __restrict__ WbT) {
    int idx = blockIdx.x * 256 + threadIdx.x;   // 32768
    int j = idx & 7;
    int l = (idx >> 3) & 63;
    int ks = (idx >> 9) & 1;
    int ctile = idx >> 10;
    int k = ks * 32 + (l >> 4) * 8 + j;
    int c = ctile * 16 + (l & 15);
    WbT[idx] = f2bf(Wr4[k * 512 + c]);
}

// pack Wr2,Wr3 (64x64) -> MFMA A-fragments, bf16 (4 ctiles each)
__global__ void k_wprep23(const float* __restrict__ Wr2, const float* __restrict__ Wr3,
                          unsigned short* __restrict__ WbA) {
    int idx = blockIdx.x * 256 + threadIdx.x;   // 8192
    int which = idx >> 12;
    int r = idx & 4095;
    int j = r & 7;
    int l = (r >> 3) & 63;
    int ks = (r >> 9) & 1;
    int ct = (r >> 10) & 3;
    const float* W = which ? Wr3 : Wr2;
    int k = ks * 32 + (l >> 4) * 8 + j;
    int c = ct * 16 + (l & 15);
    WbA[idx] = f2bf(W[k * 64 + c]);
}

// pack Wlin0,Wlin1 (128x128) -> MFMA A-fragments, bf16 (8 ctiles x 4 ks each)
__global__ void k_wprepL(const float* __restrict__ Wlin0, const float* __restrict__ Wlin1,
                         unsigned short* __restrict__ WlA) {
    int idx = blockIdx.x * 256 + threadIdx.x;   // 32768
    int which = idx >> 14;
    int r = idx & 16383;
    int j = r & 7;
    int l = (r >> 3) & 63;
    int ks = (r >> 9) & 3;
    int ct = r >> 11;
    const float* W = which ? Wlin1 : Wlin0;
    int k = ks * 32 + (l >> 4) * 8 + j;
    int c = ct * 16 + (l & 15);
    WlA[idx] = f2bf(W[k * 128 + c]);
}

// pack W_out (4 x 128x128) -> MFMA A-fragments, bf16 (8 ctiles x 4 ks per l)
__global__ void k_wprepO(const float* __restrict__ W_out, unsigned short* __restrict__ WoA) {
    int idx = blockIdx.x * 256 + threadIdx.x;   // 65536
    int j = idx & 7;
    int l = (idx >> 3) & 63;
    int ks = (idx >> 9) & 3;
    int ct = (idx >> 11) & 7;
    int lm = idx >> 14;
    int k = ks * 32 + (l >> 4) * 8 + j;
    int c = ct * 16 + (l & 15);
    WoA[idx] = f2bf(W_out[(size_t)lm * 16384 + k * 128 + c]);
}

// ---------------- CSR build (offsets + inverse permutation + sender element) ----------------

__global__ void k_hist(const int* __restrict__ ei, const int* __restrict__ elem,
                       int* __restrict__ deg, int* __restrict__ eel, int E) {
    int e = blockIdx.x * 256 + threadIdx.x;
    if (e < E) {
        atomicAdd(&deg[ei[E + e]], 1);
        eel[e] = elem[ei[e]];
    }
}

__global__ void k_scan(const int* __restrict__ deg, int* __restrict__ offs, int n) {
    __shared__ int sums[1024];
    int tid = threadIdx.x;
    int base = tid * 8;
    int loc[8];
    int s = 0;
#pragma unroll
    for (int i = 0; i < 8; ++i) {
        loc[i] = s;
        if (base + i < n) s += deg[base + i];
    }
    sums[tid] = s;
    __syncthreads();
    for (int st = 1; st < 1024; st <<= 1) {
        int v = 0;
        if (tid >= st) v = sums[tid - st];
        __syncthreads();
        sums[tid] += v;
        __syncthreads();
    }
    int excl = sums[tid] - s;
#pragma unroll
    for (int i = 0; i < 8; ++i)
        if (base + i < n) offs[base + i] = excl + loc[i];
    if (tid == 1023) offs[n] = sums[1023];
}

__global__ void k_scatter(const int* __restrict__ ei, const int* __restrict__ offs,
                          int* __restrict__ cur, int* __restrict__ epos, int E) {
    int e = blockIdx.x * 256 + threadIdx.x;
    if (e < E) {
        int r = ei[E + e];
        int p = atomicAdd(&cur[r], 1);
        epos[e] = offs[r] + p;
    }
}

// ---------------- edge pre-kernel: Y + radial + layer 1 only ----------------

__global__ __launch_bounds__(256, 2) void k_edge_pre(
    const float* __restrict__ evec, const float* __restrict__ elen,
    const float* __restrict__ Wr1,
    float* __restrict__ Yw, unsigned short* __restrict__ T1b, int E)
{
    const int tid = threadIdx.x;
    const int e = blockIdx.x * 256 + tid;
    if (e >= E) return;

    float vx = evec[3 * e], vy = evec[3 * e + 1], vz = evec[3 * e + 2];
    float inv = rsqrtf(vx * vx + vy * vy + vz * vz);
    float ux = vx * inv, uy = vy * inv, uz = vz * inv;

    const float s3    = 1.7320508075688772f;
    const float s5h   = 1.118033988749895f;
    const float s15   = 3.872983346207417f;
    const float s15h  = 1.9364916731037085f;
    const float s70_4 = 2.091650066335189f;
    const float s105  = 10.246950765959598f;
    const float s105_2= 5.123475382979799f;
    const float s42_4 = 1.6201851746019651f;
    const float s7_2  = 1.3228756555322954f;

    float xx = ux * ux, yy = uy * uy, zz = uz * uz;
    float4* yo = reinterpret_cast<float4*>(Yw + ((size_t)e << 4));
    yo[0] = make_float4(1.0f, s3 * ux, s3 * uy, s3 * uz);
    yo[1] = make_float4(s15 * ux * uy, s15 * uy * uz, s5h * (3.0f * zz - 1.0f), s15 * ux * uz);
    yo[2] = make_float4(s15h * (xx - yy),
                        s70_4 * uy * (3.0f * xx - yy),
                        s105 * ux * uy * uz,
                        s42_4 * uy * (5.0f * zz - 1.0f));
    yo[3] = make_float4(s7_2 * uz * (5.0f * zz - 3.0f),
                        s42_4 * ux * (5.0f * zz - 1.0f),
                        s105_2 * uz * (xx - yy),
                        s70_4 * ux * (xx - 3.0f * yy));

    float r = elen[e];
    float u = r * 0.2f;
    float u2 = u * u;
    float u5 = u2 * u2 * u;
    float env = 1.0f - 21.0f * u5 + 35.0f * u5 * u - 15.0f * u5 * u2;
    if (u >= 1.0f) env = 0.0f;
    float th = 3.14159265358979323846f * u;
    float s1 = __sinf(th), c1 = __cosf(th);
    float pref = 0.6324555320336759f * env / r;
    float ef[8];
    float sn = s1, cn = c1;
    ef[0] = pref * sn;
#pragma unroll
    for (int nn = 1; nn < 8; ++nn) {
        float sn1 = sn * c1 + cn * s1;
        float cn1 = cn * c1 - sn * s1;
        sn = sn1; cn = cn1;
        ef[nn] = pref * sn;
    }

    // layer 1: 8 -> 64 + silu
    float t[64];
#pragma unroll
    for (int j = 0; j < 64; ++j) t[j] = 0.0f;
#pragma unroll
    for (int i = 0; i < 8; ++i) {
        const float4* w1r = reinterpret_cast<const float4*>(Wr1 + i * 64);
        float efi = ef[i];
#pragma unroll
        for (int j4 = 0; j4 < 16; ++j4) {
            float4 w = w1r[j4];
            t[4 * j4 + 0] = fmaf(efi, w.x, t[4 * j4 + 0]);
            t[4 * j4 + 1] = fmaf(efi, w.y, t[4 * j4 + 1]);
            t[4 * j4 + 2] = fmaf(efi, w.z, t[4 * j4 + 2]);
            t[4 * j4 + 3] = fmaf(efi, w.w, t[4 * j4 + 3]);
        }
    }
#pragma unroll
    for (int j = 0; j < 64; ++j) {
        float v = t[j];
        t[j] = v * __builtin_amdgcn_rcpf(1.0f + __expf(-v));
    }

    // store T1 as MFMA B-fragments
    {
        const int etile = e >> 4, cc = e & 15;
#pragma unroll
        for (int ks = 0; ks < 2; ++ks) {
#pragma unroll
            for (int q = 0; q < 4; ++q) {
                const float* tp = &t[ks * 32 + q * 8];
                unsigned d0 = (unsigned)f2bf(tp[0]) | ((unsigned)f2bf(tp[1]) << 16);
                unsigned d1 = (unsigned)f2bf(tp[2]) | ((unsigned)f2bf(tp[3]) << 16);
                unsigned d2 = (unsigned)f2bf(tp[4]) | ((unsigned)f2bf(tp[5]) << 16);
                unsigned d3 = (unsigned)f2bf(tp[6]) | ((unsigned)f2bf(tp[7]) << 16);
                *reinterpret_cast<uint4*>(
                    T1b + (((size_t)(etile * 2 + ks) * 64) + q * 16 + cc) * 8) =
                    make_uint4(d0, d1, d2, d3);
            }
        }
    }
}

// ---------------- layers 2+3 via MFMA ----------------

__global__ __launch_bounds__(256) void k_l23m(
    const unsigned short* __restrict__ T1b, const unsigned short* __restrict__ WbA,
    unsigned short* __restrict__ Tb, int E)
{
    __shared__ unsigned short lb[4][32][72];
    const int lane = threadIdx.x & 63;
    const int wv = threadIdx.x >> 6;
    const int ebase = blockIdx.x * 128 + wv * 32;
    const int et0 = ebase >> 4;
    const int g = lane >> 4;
    const int rr = lane & 15;

    bf16x8 bt[2][2];
#pragma unroll
    for (int et = 0; et < 2; ++et)
#pragma unroll
        for (int ks = 0; ks < 2; ++ks)
            bt[et][ks] = *reinterpret_cast<const bf16x8*>(
                T1b + (((size_t)(et0 + et) * 2 + ks) * 64 + lane) * 8);

    const unsigned short* WA2 = WbA;
    const unsigned short* WA3 = WbA + 4096;
#pragma unroll
    for (int ct = 0; ct < 4; ++ct) {
        bf16x8 a0 = *reinterpret_cast<const bf16x8*>(WA2 + (((size_t)ct * 2 + 0) * 64 + lane) * 8);
        bf16x8 a1 = *reinterpret_cast<const bf16x8*>(WA2 + (((size_t)ct * 2 + 1) * 64 + lane) * 8);
#pragma unroll
        for (int et = 0; et < 2; ++et) {
            f32x4 acc = {0.f, 0.f, 0.f, 0.f};
            acc = __builtin_amdgcn_mfma_f32_16x16x32_bf16(a0, bt[et][0], acc, 0, 0, 0);
            acc = __builtin_amdgcn_mfma_f32_16x16x32_bf16(a1, bt[et][1], acc, 0, 0, 0);
            float v0 = acc[0] * __builtin_amdgcn_rcpf(1.0f + __expf(-acc[0]));
            float v1 = acc[1] * __builtin_amdgcn_rcpf(1.0f + __expf(-acc[1]));
            float v2 = acc[2] * __builtin_amdgcn_rcpf(1.0f + __expf(-acc[2]));
            float v3 = acc[3] * __builtin_amdgcn_rcpf(1.0f + __expf(-acc[3]));
            unsigned p0 = (unsigned)f2bf(v0) | ((unsigned)f2bf(v1) << 16);
            unsigned p1 = (unsigned)f2bf(v2) | ((unsigned)f2bf(v3) << 16);
            *reinterpret_cast<uint2*>(&lb[wv][et * 16 + rr][ct * 16 + g * 4]) =
                make_uint2(p0, p1);
        }
    }
    asm volatile("s_waitcnt lgkmcnt(0)" ::: "memory");
    __builtin_amdgcn_sched_barrier(0);

    bf16x8 bt2[2][2];
#pragma unroll
    for (int et = 0; et < 2; ++et)
#pragma unroll
        for (int ks = 0; ks < 2; ++ks)
            bt2[et][ks] = *reinterpret_cast<const bf16x8*>(
                &lb[wv][et * 16 + rr][ks * 32 + g * 8]);

#pragma unroll
    for (int ct = 0; ct < 4; ++ct) {
        bf16x8 a0 = *reinterpret_cast<const bf16x8*>(WA3 + (((size_t)ct * 2 + 0) * 64 + lane) * 8);
        bf16x8 a1 = *reinterpret_cast<const bf16x8*>(WA3 + (((size_t)ct * 2 + 1) * 64 + lane) * 8);
        int c0 = ct * 16 + g * 4;
        int ks3 = c0 >> 5;
        int q3 = (c0 >> 3) & 3;
        int joff = c0 & 7;
#pragma unroll
        for (int et = 0; et < 2; ++et) {
            f32x4 acc = {0.f, 0.f, 0.f, 0.f};
            acc = __builtin_amdgcn_mfma_f32_16x16x32_bf16(a0, bt2[et][0], acc, 0, 0, 0);
            acc = __builtin_amdgcn_mfma_f32_16x16x32_bf16(a1, bt2[et][1], acc, 0, 0, 0);
            float v0 = acc[0] * __builtin_amdgcn_rcpf(1.0f + __expf(-acc[0]));
            float v1 = acc[1] * __builtin_amdgcn_rcpf(1.0f + __expf(-acc[1]));
            float v2 = acc[2] * __builtin_amdgcn_rcpf(1.0f + __expf(-acc[2]));
            float v3 = acc[3] * __builtin_amdgcn_rcpf(1.0f + __expf(-acc[3]));
            unsigned p0 = (unsigned)f2bf(v0) | ((unsigned)f2bf(v1) << 16);
            unsigned p1 = (unsigned)f2bf(v2) | ((unsigned)f2bf(v3) << 16);
            *reinterpret_cast<uint2*>(
                Tb + (((size_t)(et0 + et) * 2 + ks3) * 64 + q3 * 16 + rr) * 8 + joff) =
                make_uint2(p0, p1);
        }
    }
}

// ---------------- layer-4 via MFMA ----------------

__global__ __launch_bounds__(256) void k_l4m(
    const unsigned short* __restrict__ Tb, const unsigned short* __restrict__ WbT,
    const int* __restrict__ eel, const int* __restrict__ epos,
    const float* __restrict__ h_elem, const float* __restrict__ Yw,
    unsigned short* __restrict__ Rw, int E)
{
    const int lane = threadIdx.x & 63;
    const int wv = threadIdx.x >> 6;
    const int ebase = blockIdx.x * 128 + wv * 32;
    const int et0 = ebase >> 4;

    bf16x8 bt[2][2];
#pragma unroll
    for (int et = 0; et < 2; ++et)
#pragma unroll
        for (int ks = 0; ks < 2; ++ks)
            bt[et][ks] = *reinterpret_cast<const bf16x8*>(
                Tb + (((size_t)(et0 + et) * 2 + ks) * 64 + lane) * 8);

    int a_[2], pe_[2];
#pragma unroll
    for (int et = 0; et < 2; ++et) {
        int e = ebase + et * 16 + (lane & 15);
        a_[et] = eel[e];
        pe_[et] = epos[e];
    }
    const int crow = (lane >> 4) * 4;

#pragma unroll 2
    for (int ctile = 0; ctile < 32; ++ctile) {
        bf16x8 aw0 = *reinterpret_cast<const bf16x8*>(
            WbT + (((size_t)ctile * 2 + 0) * 64 + lane) * 8);
        bf16x8 aw1 = *reinterpret_cast<const bf16x8*>(
            WbT + (((size_t)ctile * 2 + 1) * 64 + lane) * 8);
        int cb = ctile * 16 + crow;
        int ch = cb & 127;
#pragma unroll
        for (int et = 0; et < 2; ++et) {
            f32x4 acc = {0.f, 0.f, 0.f, 0.f};
            acc = __builtin_amdgcn_mfma_f32_16x16x32_bf16(aw0, bt[et][0], acc, 0, 0, 0);
            acc = __builtin_amdgcn_mfma_f32_16x16x32_bf16(aw1, bt[et][1], acc, 0, 0, 0);
            float4 h = *reinterpret_cast<const float4*>(h_elem + a_[et] * 128 + ch);
            float v0 = acc[0] * h.x, v1 = acc[1] * h.y;
            float v2 = acc[2] * h.z, v3 = acc[3] * h.w;
            unsigned p0 = (unsigned)f2bf(v0) | ((unsigned)f2bf(v1) << 16);
            unsigned p1 = (unsigned)f2bf(v2) | ((unsigned)f2bf(v3) << 16);
            *reinterpret_cast<uint2*>(Rw + (size_t)pe_[et] * RWS + cb) = make_uint2(p0, p1);
        }
    }

#pragma unroll
    for (int it = 0; it < 2; ++it) {
        int task = it * 64 + lane;
        int eo = task >> 2, sub = task & 3;
        int e = ebase + eo;
        int pe = epos[e];
        float4 y = *reinterpret_cast<const float4*>(Yw + ((size_t)e << 4) + sub * 4);
        *reinterpret_cast<float4*>(Rw + (size_t)pe * RWS + 512 + sub * 8) = y;
    }
}

// ---------------- gather: wave per node, NO LDS, NO barriers; m-major output ----------------

__global__ __launch_bounds__(256, 6) void k_agg(
    const int* __restrict__ offs, const unsigned short* __restrict__ Rw,
    float* __restrict__ agg, int N)
{
    const int lane = threadIdx.x & 63;
    const int wv = threadIdx.x >> 6;
    const int n = blockIdx.x * 4 + wv;
    const int beg = offs[n], end = offs[n + 1];

    float a0[16], a1[16];
#pragma unroll
    for (int m = 0; m < 16; ++m) { a0[m] = 0.f; a1[m] = 0.f; }

#pragma unroll 4
    for (int k = beg; k < end; ++k) {
        const unsigned short* row = Rw + (size_t)k * RWS;
        const ushort2* rw = reinterpret_cast<const ushort2*>(row);
        ushort2 r0 = rw[lane];
        ushort2 r1 = rw[64 + lane];
        ushort2 r2 = rw[128 + lane];
        ushort2 r3 = rw[192 + lane];
        const float4* Y4 = reinterpret_cast<const float4*>(row + 512);
        float4 y0 = Y4[0], y1 = Y4[1], y2 = Y4[2], y3 = Y4[3];
        float r0a = bf2f(r0.x), r0b = bf2f(r0.y);
        float r1a = bf2f(r1.x), r1b = bf2f(r1.y);
        float r2a = bf2f(r2.x), r2b = bf2f(r2.y);
        float r3a = bf2f(r3.x), r3b = bf2f(r3.y);
        a0[0]  = fmaf(r0a, y0.x, a0[0]);  a1[0]  = fmaf(r0b, y0.x, a1[0]);
        a0[1]  = fmaf(r1a, y0.y, a0[1]);  a1[1]  = fmaf(r1b, y0.y, a1[1]);
        a0[2]  = fmaf(r1a, y0.z, a0[2]);  a1[2]  = fmaf(r1b, y0.z, a1[2]);
        a0[3]  = fmaf(r1a, y0.w, a0[3]);  a1[3]  = fmaf(r1b, y0.w, a1[3]);
        a0[4]  = fmaf(r2a, y1.x, a0[4]);  a1[4]  = fmaf(r2b, y1.x, a1[4]);
        a0[5]  = fmaf(r2a, y1.y, a0[5]);  a1[5]  = fmaf(r2b, y1.y, a1[5]);
        a0[6]  = fmaf(r2a, y1.z, a0[6]);  a1[6]  = fmaf(r2b, y1.z, a1[6]);
        a0[7]  = fmaf(r2a, y1.w, a0[7]);  a1[7]  = fmaf(r2b, y1.w, a1[7]);
        a0[8]  = fmaf(r2a, y2.x, a0[8]);  a1[8]  = fmaf(r2b, y2.x, a1[8]);
        a0[9]  = fmaf(r3a, y2.y, a0[9]);  a1[9]  = fmaf(r3b, y2.y, a1[9]);
        a0[10] = fmaf(r3a, y2.z, a0[10]); a1[10] = fmaf(r3b, y2.z, a1[10]);
        a0[11] = fmaf(r3a, y2.w, a0[11]); a1[11] = fmaf(r3b, y2.w, a1[11]);
        a0[12] = fmaf(r3a, y3.x, a0[12]); a1[12] = fmaf(r3b, y3.x, a1[12]);
        a0[13] = fmaf(r3a, y3.y, a0[13]); a1[13] = fmaf(r3b, y3.y, a1[13]);
        a0[14] = fmaf(r3a, y3.z, a0[14]); a1[14] = fmaf(r3b, y3.z, a1[14]);
        a0[15] = fmaf(r3a, y3.w, a0[15]); a1[15] = fmaf(r3b, y3.w, a1[15]);
    }

#pragma unroll
    for (int m = 0; m < 16; ++m)
        *reinterpret_cast<float2*>(agg + ((size_t)m * N + n) * 128 + 2 * lane) =
            make_float2(a0[m] * 0.0625f, a1[m] * 0.0625f);
}

// ---------------- phase-B GEMM via MFMA: Ap[n][m][d] = agg[row][:] @ W_out[l] ----------------
// block = 64 rows (4 waves x 16-row tiles), K=128 (4 ksteps), 128 cols (8 ctiles).

__global__ __launch_bounds__(256) void k_gemmBm(
    const float* __restrict__ agg, const unsigned short* __restrict__ WoA,
    float* __restrict__ Ap, int N)
{
    __shared__ float at[64][132];
    const int tid = threadIdx.x;
    const int r0 = blockIdx.x * 64;
    const int m = r0 / N;
    const int n0 = r0 - m * N;
    const int l = (m == 0) ? 0 : (m < 4) ? 1 : (m < 9) ? 2 : 3;
    const unsigned short* WA = WoA + (size_t)l * 16384;

    // stage 64x128 f32 agg tile (coalesced)
    const float4* agg4 = reinterpret_cast<const float4*>(agg + (size_t)r0 * 128);
#pragma unroll
    for (int i = 0; i < 8; ++i) {
        int f = i * 256 + tid;
        int row = f >> 5, c4 = f & 31;
        float4 v = agg4[f];
        *reinterpret_cast<float4*>(&at[row][c4 * 4]) = v;
    }
    __syncthreads();

    const int lane = tid & 63;
    const int wv = tid >> 6;
    const int rr = lane & 15;
    const int g = lane >> 4;
    const int lrow = wv * 16 + rr;

    // B-fragments: convert 8-channel slices to bf16 in registers
    bf16x8 bt[4];
#pragma unroll
    for (int ks = 0; ks < 4; ++ks) {
        const float* src = &at[lrow][ks * 32 + g * 8];
        unsigned short tmp[8];
#pragma unroll
        for (int j = 0; j < 8; ++j) tmp[j] = f2bf(src[j]);
        bt[ks] = *reinterpret_cast<const bf16x8*>(tmp);
    }

    const int crow = g * 4;
    const int n = n0 + wv * 16 + rr;

#pragma unroll 2
    for (int ct = 0; ct < 8; ++ct) {
        bf16x8 a0 = *reinterpret_cast<const bf16x8*>(WA + (((size_t)ct * 4 + 0) * 64 + lane) * 8);
        bf16x8 a1 = *reinterpret_cast<const bf16x8*>(WA + (((size_t)ct * 4 + 1) * 64 + lane) * 8);
        bf16x8 a2 = *reinterpret_cast<const bf16x8*>(WA + (((size_t)ct * 4 + 2) * 64 + lane) * 8);
        bf16x8 a3 = *reinterpret_cast<const bf16x8*>(WA + (((size_t)ct * 4 + 3) * 64 + lane) * 8);
        f32x4 acc = {0.f, 0.f, 0.f, 0.f};
        acc = __builtin_amdgcn_mfma_f32_16x16x32_bf16(a0, bt[0], acc, 0, 0, 0);
        acc = __builtin_amdgcn_mfma_f32_16x16x32_bf16(a1, bt[1], acc, 0, 0, 0);
        acc = __builtin_amdgcn_mfma_f32_16x16x32_bf16(a2, bt[2], acc, 0, 0, 0);
        acc = __builtin_amdgcn_mfma_f32_16x16x32_bf16(a3, bt[3], acc, 0, 0, 0);
        int cb = ct * 16 + crow;
        *reinterpret_cast<float4*>(Ap + (size_t)n * 2048 + m * 128 + cb) =
            make_float4(acc[0], acc[1], acc[2], acc[3]);
    }
}

// ---------------- node phase C: norms + poly; packs P as bf16 MFMA B-fragments ----------------
// 8 nodes/block. Pb0 rows = node n (p0); Pb1 rows = n*3 + (r-1) (A1*q1 rows).

__global__ __launch_bounds__(256) void k_nodeC(
    const int* __restrict__ elem, const float* __restrict__ Ap,
    const float* __restrict__ Wp0, const float* __restrict__ Wp1,
    unsigned short* __restrict__ Pb0, unsigned short* __restrict__ Pb1, int N)
{
    __shared__ float p_lds[8][4][132];
    const int tid = threadIdx.x;
    const int nbase = blockIdx.x * 8;

    {
        const int d = tid & 127;
        const int hb = tid >> 7;
#pragma unroll
        for (int qq = 0; qq < 4; ++qq) {
            int ni = hb * 4 + qq;
            int n = nbase + ni;
            int a = elem[n];
            const float* ap = Ap + (size_t)n * 2048 + d;
            float Am[16];
#pragma unroll
            for (int m = 0; m < 16; ++m)
                Am[m] = ap[m * 128];
            float s = Am[0];
            float n1 = Am[1] * Am[1] + Am[2] * Am[2] + Am[3] * Am[3];
            float n2 = Am[4] * Am[4] + Am[5] * Am[5] + Am[6] * Am[6] + Am[7] * Am[7] + Am[8] * Am[8];
            float n3 = Am[9] * Am[9] + Am[10] * Am[10] + Am[11] * Am[11] + Am[12] * Am[12] +
                       Am[13] * Am[13] + Am[14] * Am[14] + Am[15] * Am[15];
            float s2 = s * s;
            float B0v[9] = {s, s2, s2 * s, n1, n2, n3, s * n1, s * n2, s * n3};
            const float* wp0 = Wp0 + (size_t)(a * 9) * 128 + d;
            float p0 = 0.f;
#pragma unroll
            for (int b = 0; b < 9; ++b) p0 = fmaf(wp0[b * 128], B0v[b], p0);
            float coefv[6] = {1.0f, s, s2, n1, n2, n3};
            const float* wp1 = Wp1 + (size_t)(a * 6) * 128 + d;
            float q1 = 0.f;
#pragma unroll
            for (int b = 0; b < 6; ++b) q1 = fmaf(wp1[b * 128], coefv[b], q1);
            p_lds[ni][0][d] = p0;
            p_lds[ni][1][d] = Am[1] * q1;
            p_lds[ni][2][d] = Am[2] * q1;
            p_lds[ni][3][d] = Am[3] * q1;
        }
    }
    __syncthreads();

    // pack Pb0: 8 rows x 16 chunks = 128 tasks
    if (tid < 128) {
        int rl = tid >> 4;
        int cb8 = (tid & 15) * 8;
        int ks = cb8 >> 5;
        int g = (cb8 >> 3) & 3;
        int grow = nbase + rl;
        int rt = grow >> 4, rr = grow & 15;
        const float* pp = &p_lds[rl][0][cb8];
        unsigned d0 = (unsigned)f2bf(pp[0]) | ((unsigned)f2bf(pp[1]) << 16);
        unsigned d1 = (unsigned)f2bf(pp[2]) | ((unsigned)f2bf(pp[3]) << 16);
        unsigned d2 = (unsigned)f2bf(pp[4]) | ((unsigned)f2bf(pp[5]) << 16);
        unsigned d3 = (unsigned)f2bf(pp[6]) | ((unsigned)f2bf(pp[7]) << 16);
        *reinterpret_cast<uint4*>(Pb0 + ((size_t)(rt * 4 + ks) * 64 + g * 16 + rr) * 8) =
            make_uint4(d0, d1, d2, d3);
    }
    // pack Pb1: 24 rows x 16 chunks = 384 tasks
#pragma unroll
    for (int it = 0; it < 2; ++it) {
        int task = it * 256 + tid;
        if (task < 384) {
            int rl = task >> 4;             // 0..23
            int cb8 = (task & 15) * 8;
            int ks = cb8 >> 5;
            int g = (cb8 >> 3) & 3;
            int nl = rl / 3;
            int rq = rl - nl * 3 + 1;
            int grow = nbase * 3 + rl;
            int rt = grow >> 4, rr = grow & 15;
            const float* pp = &p_lds[nl][rq][cb8];
            unsigned d0 = (unsigned)f2bf(pp[0]) | ((unsigned)f2bf(pp[1]) << 16);
            unsigned d1 = (unsigned)f2bf(pp[2]) | ((unsigned)f2bf(pp[3]) << 16);
            unsigned d2 = (unsigned)f2bf(pp[4]) | ((unsigned)f2bf(pp[5]) << 16);
            unsigned d3 = (unsigned)f2bf(pp[6]) | ((unsigned)f2bf(pp[7]) << 16);
            *reinterpret_cast<uint4*>(Pb1 + ((size_t)(rt * 4 + ks) * 64 + g * 16 + rr) * 8) =
                make_uint4(d0, d1, d2, d3);
        }
    }
}

// ---------------- node phase D via MFMA: out rows = P @ Wlin (+sc0 row0) ----------------

__global__ __launch_bounds__(256) void k_nodeD(
    const unsigned short* __restrict__ Pb0, const unsigned short* __restrict__ Pb1,
    const unsigned short* __restrict__ WlA,
    const int* __restrict__ elem, const float* __restrict__ sc0e,
    float* __restrict__ out, int N)
{
    const int lane = threadIdx.x & 63;
    const int wv = threadIdx.x >> 6;
    const int bid = blockIdx.x;
    const int nb1 = N / 128;
    const bool g1 = bid < nb1;
    const unsigned short* Pb = g1 ? Pb0 : Pb1;
    const unsigned short* WA = g1 ? WlA : (WlA + 16384);
    const int rowbase = (g1 ? bid : (bid - nb1)) * 128 + wv * 32;
    const int rt0 = rowbase >> 4;

    bf16x8 bt[2][4];
#pragma unroll
    for (int et = 0; et < 2; ++et)
#pragma unroll
        for (int ks = 0; ks < 4; ++ks)
            bt[et][ks] = *reinterpret_cast<const bf16x8*>(
                Pb + (((size_t)(rt0 + et) * 4 + ks) * 64 + lane) * 8);

    int n_[2], r_[2], a_[2];
#pragma unroll
    for (int et = 0; et < 2; ++et) {
        int grow = rowbase + et * 16 + (lane & 15);
        if (g1) { n_[et] = grow; r_[et] = 0; a_[et] = elem[grow]; }
        else    { n_[et] = grow / 3; r_[et] = grow - n_[et] * 3 + 1; a_[et] = 0; }
    }
    const int crow = (lane >> 4) * 4;

#pragma unroll 2
    for (int ct = 0; ct < 8; ++ct) {
        bf16x8 a0 = *reinterpret_cast<const bf16x8*>(WA + (((size_t)ct * 4 + 0) * 64 + lane) * 8);
        bf16x8 a1 = *reinterpret_cast<const bf16x8*>(WA + (((size_t)ct * 4 + 1) * 64 + lane) * 8);
        bf16x8 a2 = *reinterpret_cast<const bf16x8*>(WA + (((size_t)ct * 4 + 2) * 64 + lane) * 8);
        bf16x8 a3 = *reinterpret_cast<const bf16x8*>(WA + (((size_t)ct * 4 + 3) * 64 + lane) * 8);
        int cb = ct * 16 + crow;
#pragma unroll
        for (int et = 0; et < 2; ++et) {
            f32x4 acc = {0.f, 0.f, 0.f, 0.f};
            acc = __builtin_amdgcn_mfma_f32_16x16x32_bf16(a0, bt[et][0], acc, 0, 0, 0);
            acc = __builtin_amdgcn_mfma_f32_16x16x32_bf16(a1, bt[et][1], acc, 0, 0, 0);
            acc = __builtin_amdgcn_mfma_f32_16x16x32_bf16(a2, bt[et][2], acc, 0, 0, 0);
            acc = __builtin_amdgcn_mfma_f32_16x16x32_bf16(a3, bt[et][3], acc, 0, 0, 0);
            float4 o = make_float4(acc[0], acc[1], acc[2], acc[3]);
            if (g1) {
                float4 sc = *reinterpret_cast<const float4*>(sc0e + (size_t)a_[et] * 128 + cb);
                o.x += sc.x; o.y += sc.y; o.z += sc.z; o.w += sc.w;
            }
            *reinterpret_cast<float4*>(
                out + (size_t)n_[et] * 512 + (size_t)r_[et] * 128 + cb) = o;
        }
    }
}

// ---------------- launcher ----------------

extern "C" void kernel_launch(void* const* d_in, const int* in_sizes, int n_in,
                              void* d_out, int out_size, void* d_ws, size_t ws_size,
                              hipStream_t stream) {
    const float* x       = (const float*)d_in[0];
    const float* evec    = (const float*)d_in[1];
    const float* elen    = (const float*)d_in[2];
    const int*   eidx    = (const int*)d_in[3];
    const float* W_embed = (const float*)d_in[4];
    const float* W_skip  = (const float*)d_in[5];
    const float* W_up    = (const float*)d_in[6];
    const float* Wr1     = (const float*)d_in[7];
    const float* Wr2     = (const float*)d_in[8];
    const float* Wr3     = (const float*)d_in[9];
    const float* Wr4     = (const float*)d_in[10];
    const float* W_out   = (const float*)d_in[11];
    const float* Wp0     = (const float*)d_in[12];
    const float* Wp1     = (const float*)d_in[13];
    const float* Wlin0   = (const float*)d_in[14];
    const float* Wlin1   = (const float*)d_in[15];
    float* out = (float*)d_out;

    const int N = in_sizes[0] / NELEM;
    const int E = in_sizes[2];

    char* base = (char*)d_ws;
    size_t off = 0;
    auto alloc = [&](size_t b) { size_t o = off; off += (b + 255) & ~(size_t)255; return o; };
    int*   elem  = (int*)(base + alloc((size_t)N * 4));
    float* helem = (float*)(base + alloc((size_t)NELEM * C * 4));
    float* sc0e  = (float*)(base + alloc((size_t)NELEM * C * 4));
    unsigned short* WbT = (unsigned short*)(base + alloc(32768 * 2));
    unsigned short* WbA = (unsigned short*)(base + alloc(8192 * 2));
    unsigned short* WlA = (unsigned short*)(base + alloc(32768 * 2));
    unsigned short* WoA = (unsigned short*)(base + alloc(65536 * 2));
    int*   deg   = (int*)(base + alloc((size_t)N * 4));
    int*   offs  = (int*)(base + alloc((size_t)(N + 1) * 4));
    int*   cur   = (int*)(base + alloc((size_t)N * 4));
    int*   epos  = (int*)(base + alloc((size_t)E * 4));
    int*   eel   = (int*)(base + alloc((size_t)E * 4));
    unsigned short* Pb0 = (unsigned short*)(base + alloc((size_t)N * 128 * 2));
    unsigned short* Pb1 = (unsigned short*)(base + alloc((size_t)N * 3 * 128 * 2));

    // region R: Rw (later reused for Ap)
    size_t szRw = (size_t)E * RWS * 2 + 256;
    size_t szAp = (size_t)N * 16 * 128 * 4;
    size_t offR = alloc(szRw > szAp ? szRw : szAp);
    unsigned short* Rw = (unsigned short*)(base + offR);
    float* Ap = (float*)(base + offR);

    // region S: Yw + T1b + Tb (agg overlays the start after Rw consumed)
    size_t szY = (size_t)E * 16 * 4;
    size_t szT1 = (size_t)E * 64 * 2;
    size_t szTb = (size_t)E * 64 * 2;
    size_t szAgg = (size_t)N * 16 * 128 * 4;
    size_t need = szY + 256 + szT1 + 256 + szTb;
    size_t offS = alloc(need > szAgg ? need : szAgg);
    float* Yw = (float*)(base + offS);
    unsigned short* T1b = (unsigned short*)(base + ((offS + szY + 255) & ~(size_t)255));
    unsigned short* Tb  = (unsigned short*)((char*)T1b + ((szT1 + 255) & ~(size_t)255));
    float* agg = (float*)(base + offS);
    (void)n_in; (void)out_size; (void)ws_size;

    hipMemsetAsync(deg, 0, (size_t)N * 4, stream);
    hipMemsetAsync(cur, 0, (size_t)N * 4, stream);

    k_tables<<<NELEM, 128, 0, stream>>>(W_embed, W_up, W_skip, helem, sc0e);
    k_elem<<<(N + 255) / 256, 256, 0, stream>>>(x, elem, N);
    k_wprep<<<128, 256, 0, stream>>>(Wr4, WbT);
    k_wprep23<<<32, 256, 0, stream>>>(Wr2, Wr3, WbA);
    k_wprepL<<<128, 256, 0, stream>>>(Wlin0, Wlin1, WlA);
    k_wprepO<<<256, 256, 0, stream>>>(W_out, WoA);
    k_hist<<<(E + 255) / 256, 256, 0, stream>>>(eidx, elem, deg, eel, E);
    k_scan<<<1, 1024, 0, stream>>>(deg, offs, N);
    k_scatter<<<(E + 255) / 256, 256, 0, stream>>>(eidx, offs, cur, epos, E);
    k_edge_pre<<<(E + 255) / 256, 256, 0, stream>>>(evec, elen, Wr1, Yw, T1b, E);
    k_l23m<<<E / 128, 256, 0, stream>>>(T1b, WbA, Tb, E);
    k_l4m<<<E / 128, 256, 0, stream>>>(Tb, WbT, eel, epos, helem, Yw, Rw, E);
    k_agg<<<N / 4, 256, 0, stream>>>(offs, Rw, agg, N);
    k_gemmBm<<<(16 * N) / 64, 256, 0, stream>>>(agg, WoA, Ap, N);
    k_nodeC<<<N / 8, 256, 0, stream>>>(elem, Ap, Wp0, Wp1, Pb0, Pb1, N);
    k_nodeD<<<(N / 128) * 4, 256, 0, stream>>>(Pb0, Pb1, WlA, elem, sc0e, out, N);
}

// Round 22
// 225.206 us; speedup vs baseline: 1.3631x; 1.0532x over previous
//
#include <hip/hip_runtime.h>

#define NELEM 10
#define C 128
#define RWS 544   // packed row stride in ushorts: 512 bf16 R + 32 ushorts (16 f32) Y

typedef __bf16 bf16x8 __attribute__((ext_vector_type(8)));
typedef float f32x4 __attribute__((ext_vector_type(4)));

__device__ inline unsigned short f2bf(float f) {
    unsigned x = __float_as_uint(f);
    unsigned r = (x + 0x7fffu + ((x >> 16) & 1u)) >> 16;
    return (unsigned short)r;
}
__device__ inline float bf2f(unsigned short b) {
    return __uint_as_float(((unsigned)b) << 16);
}

// ---------------- small prep kernels ----------------

__global__ __launch_bounds__(128) void k_tables(
    const float* __restrict__ W_embed, const float* __restrict__ W_up,
    const float* __restrict__ W_skip,
    float* __restrict__ h_elem, float* __restrict__ sc0e) {
    const int a = blockIdx.x;
    const int c = threadIdx.x;
    float acc = 0.f, acc2 = 0.f;
#pragma unroll 4
    for (int k = 0; k < C; ++k) {
        float we = W_embed[a * C + k];
        acc  = fmaf(we, W_up[k * C + c], acc);
        acc2 = fmaf(we, W_skip[(k * NELEM + a) * C + c], acc2);
    }
    h_elem[a * C + c] = acc;
    sc0e[a * C + c] = acc2;
}

__global__ void k_elem(const float* __restrict__ x, int* __restrict__ elem, int n) {
    int i = blockIdx.x * 256 + threadIdx.x;
    if (i >= n) return;
    int a = 0;
    float best = x[i * NELEM];
    for (int j = 1; j < NELEM; ++j) {
        float v = x[i * NELEM + j];
        if (v > best) { best = v; a = j; }
    }
    elem[i] = a;
}

// pack Wr4 -> MFMA A-fragments (W^T tiles), bf16 (32 ctiles):
__global__ void k_wprep(const float* __restrict__ Wr4, unsigned short* __restrict__ WbT) {
    int idx = blockIdx.x * 256 + threadIdx.x;   // 32768
    int j = idx & 7;
    int l = (idx >> 3) & 63;
    int ks = (idx >> 9) & 1;
    int ctile = idx >> 10;
    int k = ks * 32 + (l >> 4) * 8 + j;
    int c = ctile * 16 + (l & 15);
    WbT[idx] = f2bf(Wr4[k * 512 + c]);
}

// pack Wr2,Wr3 (64x64) -> MFMA A-fragments, bf16 (4 ctiles each)
__global__ void k_wprep23(const float* __restrict__ Wr2, const float* __restrict__ Wr3,
                          unsigned short* __restrict__ WbA) {
    int idx = blockIdx.x * 256 + threadIdx.x;   // 8192
    int which = idx >> 12;
    int r = idx & 4095;
    int j = r & 7;
    int l = (r >> 3) & 63;
    int ks = (r >> 9) & 1;
    int ct = (r >> 10) & 3;
    const float* W = which ? Wr3 : Wr2;
    int k = ks * 32 + (l >> 4) * 8 + j;
    int c = ct * 16 + (l & 15);
    WbA[idx] = f2bf(W[k * 64 + c]);
}

// pack Wlin0,Wlin1 (128x128) -> MFMA A-fragments, bf16 (8 ctiles x 4 ks each)
__global__ void k_wprepL(const float* __restrict__ Wlin0, const float* __restrict__ Wlin1,
                         unsigned short* __restrict__ WlA) {
    int idx = blockIdx.x * 256 + threadIdx.x;   // 32768
    int which = idx >> 14;
    int r = idx & 16383;
    int j = r & 7;
    int l = (r >> 3) & 63;
    int ks = (r >> 9) & 3;
    int ct = r >> 11;
    const float* W = which ? Wlin1 : Wlin0;
    int k = ks * 32 + (l >> 4) * 8 + j;
    int c = ct * 16 + (l & 15);
    WlA[idx] = f2bf(W[k * 128 + c]);
}

// pack W_out (4 x 128x128) -> MFMA A-fragments, bf16 (8 ctiles x 4 ks per l)
__global__ void k_wprepO(const float* __restrict__ W_out, unsigned short* __restrict__ WoA) {
    int idx = blockIdx.x * 256 + threadIdx.x;   // 65536
    int j = idx & 7;
    int l = (idx >> 3) & 63;
    int ks = (idx >> 9) & 3;
    int ct = (idx >> 11) & 7;
    int lm = idx >> 14;
    int k = ks * 32 + (l >> 4) * 8 + j;
    int c = ct * 16 + (l & 15);
    WoA[idx] = f2bf(W_out[(size_t)lm * 16384 + k * 128 + c]);
}

// ---------------- CSR build (offsets + inverse permutation + sender element) ----------------

__global__ void k_hist(const int* __restrict__ ei, const int* __restrict__ elem,
                       int* __restrict__ deg, int* __restrict__ eel, int E) {
    int e = blockIdx.x * 256 + threadIdx.x;
    if (e < E) {
        atomicAdd(&deg[ei[E + e]], 1);
        eel[e] = elem[ei[e]];
    }
}

__global__ void k_scan(const int* __restrict__ deg, int* __restrict__ offs, int n) {
    __shared__ int sums[1024];
    int tid = threadIdx.x;
    int base = tid * 8;
    int loc[8];
    int s = 0;
#pragma unroll
    for (int i = 0; i < 8; ++i) {
        loc[i] = s;
        if (base + i < n) s += deg[base + i];
    }
    sums[tid] = s;
    __syncthreads();
    for (int st = 1; st < 1024; st <<= 1) {
        int v = 0;
        if (tid >= st) v = sums[tid - st];
        __syncthreads();
        sums[tid] += v;
        __syncthreads();
    }
    int excl = sums[tid] - s;
#pragma unroll
    for (int i = 0; i < 8; ++i)
        if (base + i < n) offs[base + i] = excl + loc[i];
    if (tid == 1023) offs[n] = sums[1023];
}

__global__ void k_scatter(const int* __restrict__ ei, const int* __restrict__ offs,
                          int* __restrict__ cur, int* __restrict__ epos, int E) {
    int e = blockIdx.x * 256 + threadIdx.x;
    if (e < E) {
        int r = ei[E + e];
        int p = atomicAdd(&cur[r], 1);
        epos[e] = offs[r] + p;
    }
}

// ---------------- edge pre-kernel: Y + radial + layer 1 only ----------------

__global__ __launch_bounds__(256, 2) void k_edge_pre(
    const float* __restrict__ evec, const float* __restrict__ elen,
    const float* __restrict__ Wr1,
    float* __restrict__ Yw, unsigned short* __restrict__ T1b, int E)
{
    const int tid = threadIdx.x;
    const int e = blockIdx.x * 256 + tid;
    if (e >= E) return;

    float vx = evec[3 * e], vy = evec[3 * e + 1], vz = evec[3 * e + 2];
    float inv = rsqrtf(vx * vx + vy * vy + vz * vz);
    float ux = vx * inv, uy = vy * inv, uz = vz * inv;

    const float s3    = 1.7320508075688772f;
    const float s5h   = 1.118033988749895f;
    const float s15   = 3.872983346207417f;
    const float s15h  = 1.9364916731037085f;
    const float s70_4 = 2.091650066335189f;
    const float s105  = 10.246950765959598f;
    const float s105_2= 5.123475382979799f;
    const float s42_4 = 1.6201851746019651f;
    const float s7_2  = 1.3228756555322954f;

    float xx = ux * ux, yy = uy * uy, zz = uz * uz;
    float4* yo = reinterpret_cast<float4*>(Yw + ((size_t)e << 4));
    yo[0] = make_float4(1.0f, s3 * ux, s3 * uy, s3 * uz);
    yo[1] = make_float4(s15 * ux * uy, s15 * uy * uz, s5h * (3.0f * zz - 1.0f), s15 * ux * uz);
    yo[2] = make_float4(s15h * (xx - yy),
                        s70_4 * uy * (3.0f * xx - yy),
                        s105 * ux * uy * uz,
                        s42_4 * uy * (5.0f * zz - 1.0f));
    yo[3] = make_float4(s7_2 * uz * (5.0f * zz - 3.0f),
                        s42_4 * ux * (5.0f * zz - 1.0f),
                        s105_2 * uz * (xx - yy),
                        s70_4 * ux * (xx - 3.0f * yy));

    float r = elen[e];
    float u = r * 0.2f;
    float u2 = u * u;
    float u5 = u2 * u2 * u;
    float env = 1.0f - 21.0f * u5 + 35.0f * u5 * u - 15.0f * u5 * u2;
    if (u >= 1.0f) env = 0.0f;
    float th = 3.14159265358979323846f * u;
    float s1 = __sinf(th), c1 = __cosf(th);
    float pref = 0.6324555320336759f * env / r;
    float ef[8];
    float sn = s1, cn = c1;
    ef[0] = pref * sn;
#pragma unroll
    for (int nn = 1; nn < 8; ++nn) {
        float sn1 = sn * c1 + cn * s1;
        float cn1 = cn * c1 - sn * s1;
        sn = sn1; cn = cn1;
        ef[nn] = pref * sn;
    }

    // layer 1: 8 -> 64 + silu
    float t[64];
#pragma unroll
    for (int j = 0; j < 64; ++j) t[j] = 0.0f;
#pragma unroll
    for (int i = 0; i < 8; ++i) {
        const float4* w1r = reinterpret_cast<const float4*>(Wr1 + i * 64);
        float efi = ef[i];
#pragma unroll
        for (int j4 = 0; j4 < 16; ++j4) {
            float4 w = w1r[j4];
            t[4 * j4 + 0] = fmaf(efi, w.x, t[4 * j4 + 0]);
            t[4 * j4 + 1] = fmaf(efi, w.y, t[4 * j4 + 1]);
            t[4 * j4 + 2] = fmaf(efi, w.z, t[4 * j4 + 2]);
            t[4 * j4 + 3] = fmaf(efi, w.w, t[4 * j4 + 3]);
        }
    }
#pragma unroll
    for (int j = 0; j < 64; ++j) {
        float v = t[j];
        t[j] = v * __builtin_amdgcn_rcpf(1.0f + __expf(-v));
    }

    // store T1 as MFMA B-fragments
    {
        const int etile = e >> 4, cc = e & 15;
#pragma unroll
        for (int ks = 0; ks < 2; ++ks) {
#pragma unroll
            for (int q = 0; q < 4; ++q) {
                const float* tp = &t[ks * 32 + q * 8];
                unsigned d0 = (unsigned)f2bf(tp[0]) | ((unsigned)f2bf(tp[1]) << 16);
                unsigned d1 = (unsigned)f2bf(tp[2]) | ((unsigned)f2bf(tp[3]) << 16);
                unsigned d2 = (unsigned)f2bf(tp[4]) | ((unsigned)f2bf(tp[5]) << 16);
                unsigned d3 = (unsigned)f2bf(tp[6]) | ((unsigned)f2bf(tp[7]) << 16);
                *reinterpret_cast<uint4*>(
                    T1b + (((size_t)(etile * 2 + ks) * 64) + q * 16 + cc) * 8) =
                    make_uint4(d0, d1, d2, d3);
            }
        }
    }
}

// ---------------- layers 2+3 via MFMA ----------------

__global__ __launch_bounds__(256) void k_l23m(
    const unsigned short* __restrict__ T1b, const unsigned short* __restrict__ WbA,
    unsigned short* __restrict__ Tb, int E)
{
    __shared__ unsigned short lb[4][32][72];
    const int lane = threadIdx.x & 63;
    const int wv = threadIdx.x >> 6;
    const int ebase = blockIdx.x * 128 + wv * 32;
    const int et0 = ebase >> 4;
    const int g = lane >> 4;
    const int rr = lane & 15;

    bf16x8 bt[2][2];
#pragma unroll
    for (int et = 0; et < 2; ++et)
#pragma unroll
        for (int ks = 0; ks < 2; ++ks)
            bt[et][ks] = *reinterpret_cast<const bf16x8*>(
                T1b + (((size_t)(et0 + et) * 2 + ks) * 64 + lane) * 8);

    const unsigned short* WA2 = WbA;
    const unsigned short* WA3 = WbA + 4096;
#pragma unroll
    for (int ct = 0; ct < 4; ++ct) {
        bf16x8 a0 = *reinterpret_cast<const bf16x8*>(WA2 + (((size_t)ct * 2 + 0) * 64 + lane) * 8);
        bf16x8 a1 = *reinterpret_cast<const bf16x8*>(WA2 + (((size_t)ct * 2 + 1) * 64 + lane) * 8);
#pragma unroll
        for (int et = 0; et < 2; ++et) {
            f32x4 acc = {0.f, 0.f, 0.f, 0.f};
            acc = __builtin_amdgcn_mfma_f32_16x16x32_bf16(a0, bt[et][0], acc, 0, 0, 0);
            acc = __builtin_amdgcn_mfma_f32_16x16x32_bf16(a1, bt[et][1], acc, 0, 0, 0);
            float v0 = acc[0] * __builtin_amdgcn_rcpf(1.0f + __expf(-acc[0]));
            float v1 = acc[1] * __builtin_amdgcn_rcpf(1.0f + __expf(-acc[1]));
            float v2 = acc[2] * __builtin_amdgcn_rcpf(1.0f + __expf(-acc[2]));
            float v3 = acc[3] * __builtin_amdgcn_rcpf(1.0f + __expf(-acc[3]));
            unsigned p0 = (unsigned)f2bf(v0) | ((unsigned)f2bf(v1) << 16);
            unsigned p1 = (unsigned)f2bf(v2) | ((unsigned)f2bf(v3) << 16);
            *reinterpret_cast<uint2*>(&lb[wv][et * 16 + rr][ct * 16 + g * 4]) =
                make_uint2(p0, p1);
        }
    }
    asm volatile("s_waitcnt lgkmcnt(0)" ::: "memory");
    __builtin_amdgcn_sched_barrier(0);

    bf16x8 bt2[2][2];
#pragma unroll
    for (int et = 0; et < 2; ++et)
#pragma unroll
        for (int ks = 0; ks < 2; ++ks)
            bt2[et][ks] = *reinterpret_cast<const bf16x8*>(
                &lb[wv][et * 16 + rr][ks * 32 + g * 8]);

#pragma unroll
    for (int ct = 0; ct < 4; ++ct) {
        bf16x8 a0 = *reinterpret_cast<const bf16x8*>(WA3 + (((size_t)ct * 2 + 0) * 64 + lane) * 8);
        bf16x8 a1 = *reinterpret_cast<const bf16x8*>(WA3 + (((size_t)ct * 2 + 1) * 64 + lane) * 8);
        int c0 = ct * 16 + g * 4;
        int ks3 = c0 >> 5;
        int q3 = (c0 >> 3) & 3;
        int joff = c0 & 7;
#pragma unroll
        for (int et = 0; et < 2; ++et) {
            f32x4 acc = {0.f, 0.f, 0.f, 0.f};
            acc = __builtin_amdgcn_mfma_f32_16x16x32_bf16(a0, bt2[et][0], acc, 0, 0, 0);
            acc = __builtin_amdgcn_mfma_f32_16x16x32_bf16(a1, bt2[et][1], acc, 0, 0, 0);
            float v0 = acc[0] * __builtin_amdgcn_rcpf(1.0f + __expf(-acc[0]));
            float v1 = acc[1] * __builtin_amdgcn_rcpf(1.0f + __expf(-acc[1]));
            float v2 = acc[2] * __builtin_amdgcn_rcpf(1.0f + __expf(-acc[2]));
            float v3 = acc[3] * __builtin_amdgcn_rcpf(1.0f + __expf(-acc[3]));
            unsigned p0 = (unsigned)f2bf(v0) | ((unsigned)f2bf(v1) << 16);
            unsigned p1 = (unsigned)f2bf(v2) | ((unsigned)f2bf(v3) << 16);
            *reinterpret_cast<uint2*>(
                Tb + (((size_t)(et0 + et) * 2 + ks3) * 64 + q3 * 16 + rr) * 8 + joff) =
                make_uint2(p0, p1);
        }
    }
}

// ---------------- layer-4 via MFMA ----------------

__global__ __launch_bounds__(256) void k_l4m(
    const unsigned short* __restrict__ Tb, const unsigned short* __restrict__ WbT,
    const int* __restrict__ eel, const int* __restrict__ epos,
    const float* __restrict__ h_elem, const float* __restrict__ Yw,
    unsigned short* __restrict__ Rw, int E)
{
    const int lane = threadIdx.x & 63;
    const int wv = threadIdx.x >> 6;
    const int ebase = blockIdx.x * 128 + wv * 32;
    const int et0 = ebase >> 4;

    bf16x8 bt[2][2];
#pragma unroll
    for (int et = 0; et < 2; ++et)
#pragma unroll
        for (int ks = 0; ks < 2; ++ks)
            bt[et][ks] = *reinterpret_cast<const bf16x8*>(
                Tb + (((size_t)(et0 + et) * 2 + ks) * 64 + lane) * 8);

    int a_[2], pe_[2];
#pragma unroll
    for (int et = 0; et < 2; ++et) {
        int e = ebase + et * 16 + (lane & 15);
        a_[et] = eel[e];
        pe_[et] = epos[e];
    }
    const int crow = (lane >> 4) * 4;

#pragma unroll 2
    for (int ctile = 0; ctile < 32; ++ctile) {
        bf16x8 aw0 = *reinterpret_cast<const bf16x8*>(
            WbT + (((size_t)ctile * 2 + 0) * 64 + lane) * 8);
        bf16x8 aw1 = *reinterpret_cast<const bf16x8*>(
            WbT + (((size_t)ctile * 2 + 1) * 64 + lane) * 8);
        int cb = ctile * 16 + crow;
        int ch = cb & 127;
#pragma unroll
        for (int et = 0; et < 2; ++et) {
            f32x4 acc = {0.f, 0.f, 0.f, 0.f};
            acc = __builtin_amdgcn_mfma_f32_16x16x32_bf16(aw0, bt[et][0], acc, 0, 0, 0);
            acc = __builtin_amdgcn_mfma_f32_16x16x32_bf16(aw1, bt[et][1], acc, 0, 0, 0);
            float4 h = *reinterpret_cast<const float4*>(h_elem + a_[et] * 128 + ch);
            float v0 = acc[0] * h.x, v1 = acc[1] * h.y;
            float v2 = acc[2] * h.z, v3 = acc[3] * h.w;
            unsigned p0 = (unsigned)f2bf(v0) | ((unsigned)f2bf(v1) << 16);
            unsigned p1 = (unsigned)f2bf(v2) | ((unsigned)f2bf(v3) << 16);
            *reinterpret_cast<uint2*>(Rw + (size_t)pe_[et] * RWS + cb) = make_uint2(p0, p1);
        }
    }

#pragma unroll
    for (int it = 0; it < 2; ++it) {
        int task = it * 64 + lane;
        int eo = task >> 2, sub = task & 3;
        int e = ebase + eo;
        int pe = epos[e];
        float4 y = *reinterpret_cast<const float4*>(Yw + ((size_t)e << 4) + sub * 4);
        *reinterpret_cast<float4*>(Rw + (size_t)pe * RWS + 512 + sub * 8) = y;
    }
}

// ---------------- gather: wave per node; outputs agg as bf16 MFMA B-fragments ----------------
// aggB rows r = m*N + n (m-major); per-wave LDS repack, no barriers.

__global__ __launch_bounds__(256, 4) void k_agg(
    const int* __restrict__ offs, const unsigned short* __restrict__ Rw,
    unsigned short* __restrict__ aggB, int N)
{
    __shared__ float ws[4][16][132];
    const int lane = threadIdx.x & 63;
    const int wv = threadIdx.x >> 6;
    const int n = blockIdx.x * 4 + wv;
    const int beg = offs[n], end = offs[n + 1];

    float a0[16], a1[16];
#pragma unroll
    for (int m = 0; m < 16; ++m) { a0[m] = 0.f; a1[m] = 0.f; }

#pragma unroll 4
    for (int k = beg; k < end; ++k) {
        const unsigned short* row = Rw + (size_t)k * RWS;
        const ushort2* rw = reinterpret_cast<const ushort2*>(row);
        ushort2 r0 = rw[lane];
        ushort2 r1 = rw[64 + lane];
        ushort2 r2 = rw[128 + lane];
        ushort2 r3 = rw[192 + lane];
        const float4* Y4 = reinterpret_cast<const float4*>(row + 512);
        float4 y0 = Y4[0], y1 = Y4[1], y2 = Y4[2], y3 = Y4[3];
        float r0a = bf2f(r0.x), r0b = bf2f(r0.y);
        float r1a = bf2f(r1.x), r1b = bf2f(r1.y);
        float r2a = bf2f(r2.x), r2b = bf2f(r2.y);
        float r3a = bf2f(r3.x), r3b = bf2f(r3.y);
        a0[0]  = fmaf(r0a, y0.x, a0[0]);  a1[0]  = fmaf(r0b, y0.x, a1[0]);
        a0[1]  = fmaf(r1a, y0.y, a0[1]);  a1[1]  = fmaf(r1b, y0.y, a1[1]);
        a0[2]  = fmaf(r1a, y0.z, a0[2]);  a1[2]  = fmaf(r1b, y0.z, a1[2]);
        a0[3]  = fmaf(r1a, y0.w, a0[3]);  a1[3]  = fmaf(r1b, y0.w, a1[3]);
        a0[4]  = fmaf(r2a, y1.x, a0[4]);  a1[4]  = fmaf(r2b, y1.x, a1[4]);
        a0[5]  = fmaf(r2a, y1.y, a0[5]);  a1[5]  = fmaf(r2b, y1.y, a1[5]);
        a0[6]  = fmaf(r2a, y1.z, a0[6]);  a1[6]  = fmaf(r2b, y1.z, a1[6]);
        a0[7]  = fmaf(r2a, y1.w, a0[7]);  a1[7]  = fmaf(r2b, y1.w, a1[7]);
        a0[8]  = fmaf(r2a, y2.x, a0[8]);  a1[8]  = fmaf(r2b, y2.x, a1[8]);
        a0[9]  = fmaf(r3a, y2.y, a0[9]);  a1[9]  = fmaf(r3b, y2.y, a1[9]);
        a0[10] = fmaf(r3a, y2.z, a0[10]); a1[10] = fmaf(r3b, y2.z, a1[10]);
        a0[11] = fmaf(r3a, y2.w, a0[11]); a1[11] = fmaf(r3b, y2.w, a1[11]);
        a0[12] = fmaf(r3a, y3.x, a0[12]); a1[12] = fmaf(r3b, y3.x, a1[12]);
        a0[13] = fmaf(r3a, y3.y, a0[13]); a1[13] = fmaf(r3b, y3.y, a1[13]);
        a0[14] = fmaf(r3a, y3.z, a0[14]); a1[14] = fmaf(r3b, y3.z, a1[14]);
        a0[15] = fmaf(r3a, y3.w, a0[15]); a1[15] = fmaf(r3b, y3.w, a1[15]);
    }

    // stage to per-wave LDS: ws[wv][m][ch], lane owns ch 2*lane, 2*lane+1
#pragma unroll
    for (int m = 0; m < 16; ++m)
        *reinterpret_cast<float2*>(&ws[wv][m][2 * lane]) =
            make_float2(a0[m] * 0.0625f, a1[m] * 0.0625f);
    asm volatile("s_waitcnt lgkmcnt(0)" ::: "memory");
    __builtin_amdgcn_sched_barrier(0);

    // repack: 256 chunk-tasks (m, ks, g) -> bf16 fragment chunks
    const int NT = N >> 4;
    const int rrn = n & 15;
    const int ntile = n >> 4;
#pragma unroll
    for (int it = 0; it < 4; ++it) {
        int task = it * 64 + lane;
        int m = task >> 4;
        int ks = (task >> 2) & 3;
        int g = task & 3;
        const float* src = &ws[wv][m][ks * 32 + g * 8];
        unsigned d0 = (unsigned)f2bf(src[0]) | ((unsigned)f2bf(src[1]) << 16);
        unsigned d1 = (unsigned)f2bf(src[2]) | ((unsigned)f2bf(src[3]) << 16);
        unsigned d2 = (unsigned)f2bf(src[4]) | ((unsigned)f2bf(src[5]) << 16);
        unsigned d3 = (unsigned)f2bf(src[6]) | ((unsigned)f2bf(src[7]) << 16);
        size_t rt = (size_t)m * NT + ntile;
        *reinterpret_cast<uint4*>(aggB + ((rt * 4 + ks) * 64 + g * 16 + rrn) * 8) =
            make_uint4(d0, d1, d2, d3);
    }
}

// ---------------- phase-B GEMM via MFMA (direct fragment loads, no LDS) ----------------
// Ap[n][m][d] = agg[row=m*N+n][:] @ W_out[l(m)]

__global__ __launch_bounds__(256) void k_gemmBm(
    const unsigned short* __restrict__ aggB, const unsigned short* __restrict__ WoA,
    float* __restrict__ Ap, int N)
{
    const int lane = threadIdx.x & 63;
    const int wv = threadIdx.x >> 6;
    const int r0 = blockIdx.x * 64;
    const int m = r0 / N;
    const int n0 = r0 - m * N;
    const int l = (m == 0) ? 0 : (m < 4) ? 1 : (m < 9) ? 2 : 3;
    const unsigned short* WA = WoA + (size_t)l * 16384;

    const int rt = (r0 >> 4) + wv;          // this wave's 16-row tile
    const int rr = lane & 15;
    const int g = lane >> 4;
    const int n = n0 + wv * 16 + rr;

    bf16x8 bt[4];
#pragma unroll
    for (int ks = 0; ks < 4; ++ks)
        bt[ks] = *reinterpret_cast<const bf16x8*>(
            aggB + (((size_t)rt * 4 + ks) * 64 + lane) * 8);

    const int crow = g * 4;
#pragma unroll 2
    for (int ct = 0; ct < 8; ++ct) {
        bf16x8 a0 = *reinterpret_cast<const bf16x8*>(WA + (((size_t)ct * 4 + 0) * 64 + lane) * 8);
        bf16x8 a1 = *reinterpret_cast<const bf16x8*>(WA + (((size_t)ct * 4 + 1) * 64 + lane) * 8);
        bf16x8 a2 = *reinterpret_cast<const bf16x8*>(WA + (((size_t)ct * 4 + 2) * 64 + lane) * 8);
        bf16x8 a3 = *reinterpret_cast<const bf16x8*>(WA + (((size_t)ct * 4 + 3) * 64 + lane) * 8);
        f32x4 acc = {0.f, 0.f, 0.f, 0.f};
        acc = __builtin_amdgcn_mfma_f32_16x16x32_bf16(a0, bt[0], acc, 0, 0, 0);
        acc = __builtin_amdgcn_mfma_f32_16x16x32_bf16(a1, bt[1], acc, 0, 0, 0);
        acc = __builtin_amdgcn_mfma_f32_16x16x32_bf16(a2, bt[2], acc, 0, 0, 0);
        acc = __builtin_amdgcn_mfma_f32_16x16x32_bf16(a3, bt[3], acc, 0, 0, 0);
        int cb = ct * 16 + crow;
        *reinterpret_cast<float4*>(Ap + (size_t)n * 2048 + m * 128 + cb) =
            make_float4(acc[0], acc[1], acc[2], acc[3]);
    }
}

// ---------------- node phase C: norms + poly; packs P as bf16 MFMA B-fragments ----------------

__global__ __launch_bounds__(256) void k_nodeC(
    const int* __restrict__ elem, const float* __restrict__ Ap,
    const float* __restrict__ Wp0, const float* __restrict__ Wp1,
    unsigned short* __restrict__ Pb0, unsigned short* __restrict__ Pb1, int N)
{
    __shared__ float p_lds[8][4][132];
    const int tid = threadIdx.x;
    const int nbase = blockIdx.x * 8;

    {
        const int d = tid & 127;
        const int hb = tid >> 7;
#pragma unroll
        for (int qq = 0; qq < 4; ++qq) {
            int ni = hb * 4 + qq;
            int n = nbase + ni;
            int a = elem[n];
            const float* ap = Ap + (size_t)n * 2048 + d;
            float Am[16];
#pragma unroll
            for (int m = 0; m < 16; ++m)
                Am[m] = ap[m * 128];
            float s = Am[0];
            float n1 = Am[1] * Am[1] + Am[2] * Am[2] + Am[3] * Am[3];
            float n2 = Am[4] * Am[4] + Am[5] * Am[5] + Am[6] * Am[6] + Am[7] * Am[7] + Am[8] * Am[8];
            float n3 = Am[9] * Am[9] + Am[10] * Am[10] + Am[11] * Am[11] + Am[12] * Am[12] +
                       Am[13] * Am[13] + Am[14] * Am[14] + Am[15] * Am[15];
            float s2 = s * s;
            float B0v[9] = {s, s2, s2 * s, n1, n2, n3, s * n1, s * n2, s * n3};
            const float* wp0 = Wp0 + (size_t)(a * 9) * 128 + d;
            float p0 = 0.f;
#pragma unroll
            for (int b = 0; b < 9; ++b) p0 = fmaf(wp0[b * 128], B0v[b], p0);
            float coefv[6] = {1.0f, s, s2, n1, n2, n3};
            const float* wp1 = Wp1 + (size_t)(a * 6) * 128 + d;
            float q1 = 0.f;
#pragma unroll
            for (int b = 0; b < 6; ++b) q1 = fmaf(wp1[b * 128], coefv[b], q1);
            p_lds[ni][0][d] = p0;
            p_lds[ni][1][d] = Am[1] * q1;
            p_lds[ni][2][d] = Am[2] * q1;
            p_lds[ni][3][d] = Am[3] * q1;
        }
    }
    __syncthreads();

    // pack Pb0: 8 rows x 16 chunks = 128 tasks
    if (tid < 128) {
        int rl = tid >> 4;
        int cb8 = (tid & 15) * 8;
        int ks = cb8 >> 5;
        int g = (cb8 >> 3) & 3;
        int grow = nbase + rl;
        int rt = grow >> 4, rr = grow & 15;
        const float* pp = &p_lds[rl][0][cb8];
        unsigned d0 = (unsigned)f2bf(pp[0]) | ((unsigned)f2bf(pp[1]) << 16);
        unsigned d1 = (unsigned)f2bf(pp[2]) | ((unsigned)f2bf(pp[3]) << 16);
        unsigned d2 = (unsigned)f2bf(pp[4]) | ((unsigned)f2bf(pp[5]) << 16);
        unsigned d3 = (unsigned)f2bf(pp[6]) | ((unsigned)f2bf(pp[7]) << 16);
        *reinterpret_cast<uint4*>(Pb0 + ((size_t)(rt * 4 + ks) * 64 + g * 16 + rr) * 8) =
            make_uint4(d0, d1, d2, d3);
    }
    // pack Pb1: 24 rows x 16 chunks = 384 tasks
#pragma unroll
    for (int it = 0; it < 2; ++it) {
        int task = it * 256 + tid;
        if (task < 384) {
            int rl = task >> 4;             // 0..23
            int cb8 = (task & 15) * 8;
            int ks = cb8 >> 5;
            int g = (cb8 >> 3) & 3;
            int nl = rl / 3;
            int rq = rl - nl * 3 + 1;
            int grow = nbase * 3 + rl;
            int rt = grow >> 4, rr = grow & 15;
            const float* pp = &p_lds[nl][rq][cb8];
            unsigned d0 = (unsigned)f2bf(pp[0]) | ((unsigned)f2bf(pp[1]) << 16);
            unsigned d1 = (unsigned)f2bf(pp[2]) | ((unsigned)f2bf(pp[3]) << 16);
            unsigned d2 = (unsigned)f2bf(pp[4]) | ((unsigned)f2bf(pp[5]) << 16);
            unsigned d3 = (unsigned)f2bf(pp[6]) | ((unsigned)f2bf(pp[7]) << 16);
            *reinterpret_cast<uint4*>(Pb1 + ((size_t)(rt * 4 + ks) * 64 + g * 16 + rr) * 8) =
                make_uint4(d0, d1, d2, d3);
        }
    }
}

// ---------------- node phase D via MFMA: out rows = P @ Wlin (+sc0 row0) ----------------

__global__ __launch_bounds__(256) void k_nodeD(
    const unsigned short* __restrict__ Pb0, const unsigned short* __restrict__ Pb1,
    const unsigned short* __restrict__ WlA,
    const int* __restrict__ elem, const float* __restrict__ sc0e,
    float* __restrict__ out, int N)
{
    const int lane = threadIdx.x & 63;
    const int wv = threadIdx.x >> 6;
    const int bid = blockIdx.x;
    const int nb1 = N / 128;
    const bool g1 = bid < nb1;
    const unsigned short* Pb = g1 ? Pb0 : Pb1;
    const unsigned short* WA = g1 ? WlA : (WlA + 16384);
    const int rowbase = (g1 ? bid : (bid - nb1)) * 128 + wv * 32;
    const int rt0 = rowbase >> 4;

    bf16x8 bt[2][4];
#pragma unroll
    for (int et = 0; et < 2; ++et)
#pragma unroll
        for (int ks = 0; ks < 4; ++ks)
            bt[et][ks] = *reinterpret_cast<const bf16x8*>(
                Pb + (((size_t)(rt0 + et) * 4 + ks) * 64 + lane) * 8);

    int n_[2], r_[2], a_[2];
#pragma unroll
    for (int et = 0; et < 2; ++et) {
        int grow = rowbase + et * 16 + (lane & 15);
        if (g1) { n_[et] = grow; r_[et] = 0; a_[et] = elem[grow]; }
        else    { n_[et] = grow / 3; r_[et] = grow - n_[et] * 3 + 1; a_[et] = 0; }
    }
    const int crow = (lane >> 4) * 4;

#pragma unroll 2
    for (int ct = 0; ct < 8; ++ct) {
        bf16x8 a0 = *reinterpret_cast<const bf16x8*>(WA + (((size_t)ct * 4 + 0) * 64 + lane) * 8);
        bf16x8 a1 = *reinterpret_cast<const bf16x8*>(WA + (((size_t)ct * 4 + 1) * 64 + lane) * 8);
        bf16x8 a2 = *reinterpret_cast<const bf16x8*>(WA + (((size_t)ct * 4 + 2) * 64 + lane) * 8);
        bf16x8 a3 = *reinterpret_cast<const bf16x8*>(WA + (((size_t)ct * 4 + 3) * 64 + lane) * 8);
        int cb = ct * 16 + crow;
#pragma unroll
        for (int et = 0; et < 2; ++et) {
            f32x4 acc = {0.f, 0.f, 0.f, 0.f};
            acc = __builtin_amdgcn_mfma_f32_16x16x32_bf16(a0, bt[et][0], acc, 0, 0, 0);
            acc = __builtin_amdgcn_mfma_f32_16x16x32_bf16(a1, bt[et][1], acc, 0, 0, 0);
            acc = __builtin_amdgcn_mfma_f32_16x16x32_bf16(a2, bt[et][2], acc, 0, 0, 0);
            acc = __builtin_amdgcn_mfma_f32_16x16x32_bf16(a3, bt[et][3], acc, 0, 0, 0);
            float4 o = make_float4(acc[0], acc[1], acc[2], acc[3]);
            if (g1) {
                float4 sc = *reinterpret_cast<const float4*>(sc0e + (size_t)a_[et] * 128 + cb);
                o.x += sc.x; o.y += sc.y; o.z += sc.z; o.w += sc.w;
            }
            *reinterpret_cast<float4*>(
                out + (size_t)n_[et] * 512 + (size_t)r_[et] * 128 + cb) = o;
        }
    }
}

// ---------------- launcher ----------------

extern "C" void kernel_launch(void* const* d_in, const int* in_sizes, int n_in,
                              void* d_out, int out_size, void* d_ws, size_t ws_size,
                              hipStream_t stream) {
    const float* x       = (const float*)d_in[0];
    const float* evec    = (const float*)d_in[1];
    const float* elen    = (const float*)d_in[2];
    const int*   eidx    = (const int*)d_in[3];
    const float* W_embed = (const float*)d_in[4];
    const float* W_skip  = (const float*)d_in[5];
    const float* W_up    = (const float*)d_in[6];
    const float* Wr1     = (const float*)d_in[7];
    const float* Wr2     = (const float*)d_in[8];
    const float* Wr3     = (const float*)d_in[9];
    const float* Wr4     = (const float*)d_in[10];
    const float* W_out   = (const float*)d_in[11];
    const float* Wp0     = (const float*)d_in[12];
    const float* Wp1     = (const float*)d_in[13];
    const float* Wlin0   = (const float*)d_in[14];
    const float* Wlin1   = (const float*)d_in[15];
    float* out = (float*)d_out;

    const int N = in_sizes[0] / NELEM;
    const int E = in_sizes[2];

    char* base = (char*)d_ws;
    size_t off = 0;
    auto alloc = [&](size_t b) { size_t o = off; off += (b + 255) & ~(size_t)255; return o; };
    int*   elem  = (int*)(base + alloc((size_t)N * 4));
    float* helem = (float*)(base + alloc((size_t)NELEM * C * 4));
    float* sc0e  = (float*)(base + alloc((size_t)NELEM * C * 4));
    unsigned short* WbT = (unsigned short*)(base + alloc(32768 * 2));
    unsigned short* WbA = (unsigned short*)(base + alloc(8192 * 2));
    unsigned short* WlA = (unsigned short*)(base + alloc(32768 * 2));
    unsigned short* WoA = (unsigned short*)(base + alloc(65536 * 2));
    int*   deg   = (int*)(base + alloc((size_t)N * 4));
    int*   offs  = (int*)(base + alloc((size_t)(N + 1) * 4));
    int*   cur   = (int*)(base + alloc((size_t)N * 4));
    int*   epos  = (int*)(base + alloc((size_t)E * 4));
    int*   eel   = (int*)(base + alloc((size_t)E * 4));
    unsigned short* Pb0 = (unsigned short*)(base + alloc((size_t)N * 128 * 2));
    unsigned short* Pb1 = (unsigned short*)(base + alloc((size_t)N * 3 * 128 * 2));

    // region R: Rw (later reused for Ap)
    size_t szRw = (size_t)E * RWS * 2 + 256;
    size_t szAp = (size_t)N * 16 * 128 * 4;
    size_t offR = alloc(szRw > szAp ? szRw : szAp);
    unsigned short* Rw = (unsigned short*)(base + offR);
    float* Ap = (float*)(base + offR);

    // region S: Yw + T1b + Tb (aggB overlays the start after Rw consumed)
    size_t szY = (size_t)E * 16 * 4;
    size_t szT1 = (size_t)E * 64 * 2;
    size_t szTb = (size_t)E * 64 * 2;
    size_t szAggB = (size_t)N * 16 * 128 * 2;
    size_t need = szY + 256 + szT1 + 256 + szTb;
    size_t offS = alloc(need > szAggB ? need : szAggB);
    float* Yw = (float*)(base + offS);
    unsigned short* T1b = (unsigned short*)(base + ((offS + szY + 255) & ~(size_t)255));
    unsigned short* Tb  = (unsigned short*)((char*)T1b + ((szT1 + 255) & ~(size_t)255));
    unsigned short* aggB = (unsigned short*)(base + offS);
    (void)n_in; (void)out_size; (void)ws_size;

    hipMemsetAsync(deg, 0, (size_t)N * 4, stream);
    hipMemsetAsync(cur, 0, (size_t)N * 4, stream);

    k_tables<<<NELEM, 128, 0, stream>>>(W_embed, W_up, W_skip, helem, sc0e);
    k_elem<<<(N + 255) / 256, 256, 0, stream>>>(x, elem, N);
    k_wprep<<<128, 256, 0, stream>>>(Wr4, WbT);
    k_wprep23<<<32, 256, 0, stream>>>(Wr2, Wr3, WbA);
    k_wprepL<<<128, 256, 0, stream>>>(Wlin0, Wlin1, WlA);
    k_wprepO<<<256, 256, 0, stream>>>(W_out, WoA);
    k_hist<<<(E + 255) / 256, 256, 0, stream>>>(eidx, elem, deg, eel, E);
    k_scan<<<1, 1024, 0, stream>>>(deg, offs, N);
    k_scatter<<<(E + 255) / 256, 256, 0, stream>>>(eidx, offs, cur, epos, E);
    k_edge_pre<<<(E + 255) / 256, 256, 0, stream>>>(evec, elen, Wr1, Yw, T1b, E);
    k_l23m<<<E / 128, 256, 0, stream>>>(T1b, WbA, Tb, E);
    k_l4m<<<E / 128, 256, 0, stream>>>(Tb, WbT, eel, epos, helem, Yw, Rw, E);
    k_agg<<<N / 4, 256, 0, stream>>>(offs, Rw, aggB, N);
    k_gemmBm<<<(16 * N) / 64, 256, 0, stream>>>(aggB, WoA, Ap, N);
    k_nodeC<<<N / 8, 256, 0, stream>>>(elem, Ap, Wp0, Wp1, Pb0, Pb1, N);
    k_nodeD<<<(N / 128) * 4, 256, 0, stream>>>(Pb0, Pb1, WlA, elem, sc0e, out, N);
}